// Round 4
// baseline (726.276 us; speedup 1.0000x reference)
//
#include <hip/hip_runtime.h>

#define NN 50000
#define NE 800000
#define FD 64
#define PD 20
#define NG 500

// ---------------- setup kernels ----------------

__global__ void k_deg(const int* __restrict__ dst, int* __restrict__ deg) {
    int e = blockIdx.x * 256 + threadIdx.x;
    if (e < NE) atomicAdd(&deg[dst[e]], 1);
}

__global__ void k_dinv(const int* __restrict__ deg, float* __restrict__ dinv) {
    int i = blockIdx.x * 256 + threadIdx.x;
    if (i < NN) dinv[i] = rsqrtf((float)deg[i] + 1.0f);
}

// inclusive scan of deg within 256-blocks; rowp[idx+1] = partial inclusive, bsum[b] = block total
__global__ void k_scan1(const int* __restrict__ deg, int* __restrict__ rowp, int* __restrict__ bsum) {
    __shared__ int lds[256];
    int t = threadIdx.x;
    int idx = blockIdx.x * 256 + t;
    int v = (idx < NN) ? deg[idx] : 0;
    lds[t] = v;
    __syncthreads();
    for (int off = 1; off < 256; off <<= 1) {
        int add = (t >= off) ? lds[t - off] : 0;
        __syncthreads();
        lds[t] += add;
        __syncthreads();
    }
    if (idx < NN) rowp[idx + 1] = lds[t];
    if (t == 255) bsum[blockIdx.x] = lds[255];
}

__global__ void k_scan2(int* bsum, int nB) {
    __shared__ int lds[256];
    int t = threadIdx.x;
    lds[t] = (t < nB) ? bsum[t] : 0;
    __syncthreads();
    for (int off = 1; off < 256; off <<= 1) {
        int add = (t >= off) ? lds[t - off] : 0;
        __syncthreads();
        lds[t] += add;
        __syncthreads();
    }
    if (t < nB) bsum[t] = lds[t];
}

__global__ void k_scan3(int* __restrict__ rowp, const int* __restrict__ bsum) {
    int idx = blockIdx.x * 256 + threadIdx.x;
    if (idx == 0) rowp[0] = 0;
    if (blockIdx.x > 0 && idx < NN) rowp[idx + 1] += bsum[blockIdx.x - 1];
}

__global__ void k_fill_init(const int* __restrict__ rowp, int* __restrict__ fill) {
    int i = blockIdx.x * 256 + threadIdx.x;
    if (i < NN) fill[i] = rowp[i];
}

// meta[pos] = {src, bits(dinv[src])} ; dinv[dst] is factored out and applied in k_dual
__global__ void k_csr_fill(const int* __restrict__ srcA, const int* __restrict__ dstA,
                           const float* __restrict__ dinv,
                           int* __restrict__ fill, int2* __restrict__ meta) {
    int e = blockIdx.x * 256 + threadIdx.x;
    if (e < NE) {
        int s = srcA[e], d = dstA[e];
        int pos = atomicAdd(&fill[d], 1);
        int2 m;
        m.x = s;
        m.y = __float_as_int(dinv[s]);
        meta[pos] = m;
    }
}

// ---------------- degree sort (counting sort, 64 bins) ----------------

__global__ void k_dhist(const int* __restrict__ deg, int* __restrict__ dhist) {
    int i = blockIdx.x * 256 + threadIdx.x;
    if (i < NN) atomicAdd(&dhist[min(deg[i], 63)], 1);
}

__global__ void k_dscan(int* dhist) {
    // single thread exclusive scan over 64 bins (trivial)
    if (threadIdx.x == 0) {
        int acc = 0;
        for (int i = 0; i < 64; i++) { int v = dhist[i]; dhist[i] = acc; acc += v; }
    }
}

__global__ void k_dscatter(const int* __restrict__ deg, int* __restrict__ dcnt,
                           int* __restrict__ perm) {
    int i = blockIdx.x * 256 + threadIdx.x;
    if (i < NN) {
        int b = min(deg[i], 63);
        int pos = atomicAdd(&dcnt[b], 1);
        perm[pos] = i;
    }
}

// ---------------- compute kernels ----------------

// pe = RWPE @ W_rw + b_rw ; h = x + pe   (4 nodes per 256-block)
__global__ void k_pe(const float* __restrict__ x, const float* __restrict__ rwpe,
                     const float* __restrict__ Wrw, const float* __restrict__ brw,
                     float* __restrict__ pe, float* __restrict__ h) {
    __shared__ float Wl[PD * FD];
    __shared__ float rows[4 * PD];
    int t = threadIdx.x;
    int nodeBase = blockIdx.x * 4;
    for (int i = t; i < PD * FD; i += 256) Wl[i] = Wrw[i];
    if (t < 4 * PD) {
        int n = nodeBase + t / PD;
        rows[t] = (n < NN) ? rwpe[n * PD + (t % PD)] : 0.f;
    }
    __syncthreads();
    int f = t & 63, sl = t >> 6;
    int node = nodeBase + sl;
    if (node < NN) {
        float acc = brw[f];
        #pragma unroll
        for (int k = 0; k < PD; k++) acc += rows[sl * PD + k] * Wl[k * FD + f];
        pe[node * FD + f] = acc;
        h[node * FD + f] = x[node * FD + f] + acc;
    }
}

// Fused dual GCN conv (linearity: agg then GEMM):
//   oh = [relu]( aggn(hs_in) @ Wc + bc )
//   if !FINAL:  op = relu( aggn(pe_in) @ Wp + bp );  pe_out = op;  hs_out = oh + op
//   if FINAL:   hs_out = oh  (no relu)
// aggn(a)[i] = dinv_i * sum_e dinv_s a[s] + dinv_i^2 a[i]
// 16 nodes per 256-thread block, nodes taken via degree-sorted perm (divergence-free waves).
template <bool FINAL>
__global__ __launch_bounds__(256) void k_dual(
    const float* __restrict__ hs_in, const float* __restrict__ pe_in,
    const float* __restrict__ dinv, const int* __restrict__ rowp,
    const int2* __restrict__ meta, const int* __restrict__ perm,
    const float* __restrict__ Wc, const float* __restrict__ bc,
    const float* __restrict__ Wp, const float* __restrict__ bp,
    float* __restrict__ hs_out, float* __restrict__ pe_out)
{
    __shared__ float Wl[64 * 64];       // 16 KB, restaged Wc -> Wp
    __shared__ float aggH[16 * 68];
    __shared__ float aggP[16 * 68];
    int t = threadIdx.x;

    // stage Wc (1024 float4s, 4 per thread)
    {
        const float4* W4 = reinterpret_cast<const float4*>(Wc);
        float4* Wl4 = reinterpret_cast<float4*>(Wl);
        #pragma unroll
        for (int i = 0; i < 4; i++) Wl4[t + 256 * i] = W4[t + 256 * i];
    }

    int l = t & 15;           // float4 chunk within row
    int sl = t >> 4;          // node slot 0..15
    int node = perm[blockIdx.x * 16 + sl];

    float4 aH = make_float4(0.f, 0.f, 0.f, 0.f);
    float4 aP = make_float4(0.f, 0.f, 0.f, 0.f);
    int e0 = rowp[node], e1 = rowp[node + 1];
    int e = e0;
    for (; e + 4 <= e1; e += 4) {
        int2 m0 = meta[e + 0];
        int2 m1 = meta[e + 1];
        int2 m2 = meta[e + 2];
        int2 m3 = meta[e + 3];
        size_t o0 = (size_t)m0.x * 64 + l * 4;
        size_t o1 = (size_t)m1.x * 64 + l * 4;
        size_t o2 = (size_t)m2.x * 64 + l * 4;
        size_t o3 = (size_t)m3.x * 64 + l * 4;
        float4 h0v = *reinterpret_cast<const float4*>(hs_in + o0);
        float4 h1v = *reinterpret_cast<const float4*>(hs_in + o1);
        float4 h2v = *reinterpret_cast<const float4*>(hs_in + o2);
        float4 h3v = *reinterpret_cast<const float4*>(hs_in + o3);
        float4 p0v, p1v, p2v, p3v;
        if (!FINAL) {
            p0v = *reinterpret_cast<const float4*>(pe_in + o0);
            p1v = *reinterpret_cast<const float4*>(pe_in + o1);
            p2v = *reinterpret_cast<const float4*>(pe_in + o2);
            p3v = *reinterpret_cast<const float4*>(pe_in + o3);
        }
        float w0 = __int_as_float(m0.y), w1 = __int_as_float(m1.y);
        float w2 = __int_as_float(m2.y), w3 = __int_as_float(m3.y);
        aH.x += w0 * h0v.x; aH.y += w0 * h0v.y; aH.z += w0 * h0v.z; aH.w += w0 * h0v.w;
        aH.x += w1 * h1v.x; aH.y += w1 * h1v.y; aH.z += w1 * h1v.z; aH.w += w1 * h1v.w;
        aH.x += w2 * h2v.x; aH.y += w2 * h2v.y; aH.z += w2 * h2v.z; aH.w += w2 * h2v.w;
        aH.x += w3 * h3v.x; aH.y += w3 * h3v.y; aH.z += w3 * h3v.z; aH.w += w3 * h3v.w;
        if (!FINAL) {
            aP.x += w0 * p0v.x; aP.y += w0 * p0v.y; aP.z += w0 * p0v.z; aP.w += w0 * p0v.w;
            aP.x += w1 * p1v.x; aP.y += w1 * p1v.y; aP.z += w1 * p1v.z; aP.w += w1 * p1v.w;
            aP.x += w2 * p2v.x; aP.y += w2 * p2v.y; aP.z += w2 * p2v.z; aP.w += w2 * p2v.w;
            aP.x += w3 * p3v.x; aP.y += w3 * p3v.y; aP.z += w3 * p3v.z; aP.w += w3 * p3v.w;
        }
    }
    for (; e < e1; ++e) {
        int2 m = meta[e];
        size_t o = (size_t)m.x * 64 + l * 4;
        float w = __int_as_float(m.y);
        float4 hv = *reinterpret_cast<const float4*>(hs_in + o);
        aH.x += w * hv.x; aH.y += w * hv.y; aH.z += w * hv.z; aH.w += w * hv.w;
        if (!FINAL) {
            float4 pv = *reinterpret_cast<const float4*>(pe_in + o);
            aP.x += w * pv.x; aP.y += w * pv.y; aP.z += w * pv.z; aP.w += w * pv.w;
        }
    }
    {
        float dd = dinv[node];
        float4 sh = *reinterpret_cast<const float4*>(hs_in + (size_t)node * 64 + l * 4);
        float4 v;
        v.x = dd * aH.x + dd * dd * sh.x;
        v.y = dd * aH.y + dd * dd * sh.y;
        v.z = dd * aH.z + dd * dd * sh.z;
        v.w = dd * aH.w + dd * dd * sh.w;
        *reinterpret_cast<float4*>(&aggH[sl * 68 + l * 4]) = v;
        if (!FINAL) {
            float4 sp = *reinterpret_cast<const float4*>(pe_in + (size_t)node * 64 + l * 4);
            float4 u;
            u.x = dd * aP.x + dd * dd * sp.x;
            u.y = dd * aP.y + dd * dd * sp.y;
            u.z = dd * aP.z + dd * dd * sp.z;
            u.w = dd * aP.w + dd * dd * sp.w;
            *reinterpret_cast<float4*>(&aggP[sl * 68 + l * 4]) = u;
        }
    }
    __syncthreads();

    // GEMM-h: oh = aggH @ Wc + bc
    int c = t & 15;
    int sl2 = t >> 4;
    int onode = perm[blockIdx.x * 16 + sl2];
    float4 oh = *reinterpret_cast<const float4*>(bc + c * 4);
    {
        const float* arow = &aggH[sl2 * 68];
        #pragma unroll 16
        for (int k = 0; k < 64; k++) {
            float av = arow[k];
            float4 wv = *reinterpret_cast<const float4*>(&Wl[k * 64 + c * 4]);
            oh.x += av * wv.x; oh.y += av * wv.y; oh.z += av * wv.z; oh.w += av * wv.w;
        }
    }
    if (FINAL) {
        *reinterpret_cast<float4*>(hs_out + (size_t)onode * 64 + c * 4) = oh;
        return;
    }
    oh.x = fmaxf(oh.x, 0.f); oh.y = fmaxf(oh.y, 0.f);
    oh.z = fmaxf(oh.z, 0.f); oh.w = fmaxf(oh.w, 0.f);

    __syncthreads();   // everyone done reading Wc
    // restage Wp over Wl
    {
        const float4* W4 = reinterpret_cast<const float4*>(Wp);
        float4* Wl4 = reinterpret_cast<float4*>(Wl);
        #pragma unroll
        for (int i = 0; i < 4; i++) Wl4[t + 256 * i] = W4[t + 256 * i];
    }
    __syncthreads();

    // GEMM-p: op = relu(aggP @ Wp + bp)
    float4 op = *reinterpret_cast<const float4*>(bp + c * 4);
    {
        const float* arow = &aggP[sl2 * 68];
        #pragma unroll 16
        for (int k = 0; k < 64; k++) {
            float av = arow[k];
            float4 wv = *reinterpret_cast<const float4*>(&Wl[k * 64 + c * 4]);
            op.x += av * wv.x; op.y += av * wv.y; op.z += av * wv.z; op.w += av * wv.w;
        }
    }
    op.x = fmaxf(op.x, 0.f); op.y = fmaxf(op.y, 0.f);
    op.z = fmaxf(op.z, 0.f); op.w = fmaxf(op.w, 0.f);

    *reinterpret_cast<float4*>(pe_out + (size_t)onode * 64 + c * 4) = op;
    float4 sv;
    sv.x = oh.x + op.x; sv.y = oh.y + op.y; sv.z = oh.z + op.z; sv.w = oh.w + op.w;
    *reinterpret_cast<float4*>(hs_out + (size_t)onode * 64 + c * 4) = sv;
}

// ---------------- batchnorm + pool ----------------

__global__ void k_bnstats(const float* __restrict__ h, float* __restrict__ stats) {
    __shared__ float s1[256], s2[256];
    int t = threadIdx.x;
    int f = t & 63, sl = t >> 6;
    float a = 0.f, b = 0.f;
    for (int node = blockIdx.x * 4 + sl; node < NN; node += gridDim.x * 4) {
        float v = h[node * 64 + f];
        a += v;
        b += v * v;
    }
    s1[t] = a;
    s2[t] = b;
    __syncthreads();
    if (t < 64) {
        a = s1[t] + s1[t + 64] + s1[t + 128] + s1[t + 192];
        b = s2[t] + s2[t + 64] + s2[t + 128] + s2[t + 192];
        atomicAdd(&stats[t], a);
        atomicAdd(&stats[64 + t], b);
    }
}

__global__ void k_bnfinal(float* stats) {
    int f = threadIdx.x;
    if (f < 64) {
        float mu = stats[f] / (float)NN;
        float var = stats[64 + f] / (float)NN - mu * mu;
        stats[f] = mu;
        stats[64 + f] = rsqrtf(var + 1e-5f);
    }
}

__global__ void k_pool(const float* __restrict__ h, const float* __restrict__ stats,
                       const float* __restrict__ gamma, const float* __restrict__ beta,
                       const int* __restrict__ ptr, float* __restrict__ out) {
    int g = blockIdx.x;
    int f = threadIdx.x;
    int s = ptr[g], e = ptr[g + 1];
    float mu = stats[f], rstd = stats[64 + f], ga = gamma[f], be = beta[f];
    float acc = 0.f;
    for (int n = s; n < e; n++) {
        float v = (h[n * 64 + f] - mu) * rstd * ga + be;
        acc += fmaxf(v, 0.f);
    }
    out[g * 64 + f] = acc / (float)(e - s);
}

// ---------------- launch ----------------

extern "C" void kernel_launch(void* const* d_in, const int* in_sizes, int n_in,
                              void* d_out, int out_size, void* d_ws, size_t ws_size,
                              hipStream_t stream) {
    const float* x    = (const float*)d_in[0];
    const float* rwpe = (const float*)d_in[1];
    const float* Wrw  = (const float*)d_in[2];
    const float* brw  = (const float*)d_in[3];
    const float *Wc[5], *bc[5], *Wp[5], *bp[5];
    for (int i = 0; i < 5; i++) {
        Wc[i] = (const float*)d_in[4 + 4 * i];
        bc[i] = (const float*)d_in[5 + 4 * i];
        Wp[i] = (const float*)d_in[6 + 4 * i];
        bp[i] = (const float*)d_in[7 + 4 * i];
    }
    const float* gamma = (const float*)d_in[24];
    const float* beta  = (const float*)d_in[25];
    const int* ei  = (const int*)d_in[26];
    const int* ptr = (const int*)d_in[27];
    float* out = (float*)d_out;

    // workspace layout (256B aligned)
    char* wsp = (char*)d_ws;
    auto alloc = [&](size_t bytes) { void* p = (void*)wsp; wsp += ((bytes + 255) / 256) * 256; return p; };
    int*   deg   = (int*)alloc(NN * 4);
    int*   rowp  = (int*)alloc((NN + 1) * 4);
    int*   fill  = (int*)alloc(NN * 4);
    int2*  meta  = (int2*)alloc((size_t)NE * 8);
    float* dinv  = (float*)alloc(NN * 4);
    int*   perm  = (int*)alloc(NN * 4);
    int*   dhist = (int*)alloc(64 * 4);
    float* bufA  = (float*)alloc((size_t)NN * 64 * 4);   // hs ping (init h0 = x+pe)
    float* bufB  = (float*)alloc((size_t)NN * 64 * 4);   // pe ping (init pe0)
    float* bufC  = (float*)alloc((size_t)NN * 64 * 4);   // hs pong
    float* bufD  = (float*)alloc((size_t)NN * 64 * 4);   // pe pong
    float* stats = (float*)alloc(512);
    int*   bsum  = (int*)alloc(256 * 4);

    hipMemsetAsync(deg, 0, NN * 4, stream);
    hipMemsetAsync(dhist, 0, 64 * 4, stream);
    hipMemsetAsync(stats, 0, 512, stream);

    const int* srcA = ei;
    const int* dstA = ei + NE;

    dim3 b256(256);
    int gE = (NE + 255) / 256;
    int gN = (NN + 255) / 256;       // 196 blocks (<= 256, fits scan2)
    int gNode16 = NN / 16;           // 3125 (exact)

    k_deg<<<gE, b256, 0, stream>>>(dstA, deg);
    k_dinv<<<gN, b256, 0, stream>>>(deg, dinv);
    k_scan1<<<gN, b256, 0, stream>>>(deg, rowp, bsum);
    k_scan2<<<1, b256, 0, stream>>>(bsum, gN);
    k_scan3<<<gN, b256, 0, stream>>>(rowp, bsum);
    k_fill_init<<<gN, b256, 0, stream>>>(rowp, fill);
    k_csr_fill<<<gE, b256, 0, stream>>>(srcA, dstA, dinv, fill, meta);

    // degree-sorted permutation
    k_dhist<<<gN, b256, 0, stream>>>(deg, dhist);
    k_dscan<<<1, 64, 0, stream>>>(dhist);
    k_dscatter<<<gN, b256, 0, stream>>>(deg, dhist, perm);

    k_pe<<<(NN + 3) / 4, b256, 0, stream>>>(x, rwpe, Wrw, brw, bufB, bufA);

    // K0: conv1(Wc1) on bufA  +  pe-conv(Wp1) on bufB  -> hs=bufC, pe=bufD
    k_dual<false><<<gNode16, b256, 0, stream>>>(
        bufA, bufB, dinv, rowp, meta, perm,
        Wc[0], bc[0], Wp[0], bp[0], bufC, bufD);
    // K1: conv(Wc2) on bufC + pe-conv(Wp2) on bufD -> hs=bufA, pe=bufB
    k_dual<false><<<gNode16, b256, 0, stream>>>(
        bufC, bufD, dinv, rowp, meta, perm,
        Wc[1], bc[1], Wp[1], bp[1], bufA, bufB);
    // K2
    k_dual<false><<<gNode16, b256, 0, stream>>>(
        bufA, bufB, dinv, rowp, meta, perm,
        Wc[2], bc[2], Wp[2], bp[2], bufC, bufD);
    // K3
    k_dual<false><<<gNode16, b256, 0, stream>>>(
        bufC, bufD, dinv, rowp, meta, perm,
        Wc[3], bc[3], Wp[3], bp[3], bufA, bufB);
    // K4: final conv(Wc5) on bufA -> h5 = bufC (no relu)
    k_dual<true><<<gNode16, b256, 0, stream>>>(
        bufA, nullptr, dinv, rowp, meta, perm,
        Wc[4], bc[4], nullptr, nullptr, bufC, nullptr);

    k_bnstats<<<256, b256, 0, stream>>>(bufC, stats);
    k_bnfinal<<<1, 64, 0, stream>>>(stats);
    k_pool<<<NG, 64, 0, stream>>>(bufC, stats, gamma, beta, ptr, out);
}

// Round 5
// 486.292 us; speedup vs baseline: 1.4935x; 1.4935x over previous
//
#include <hip/hip_runtime.h>

#define NN 50000
#define NE 800000
#define FD 64
#define PD 20
#define NG 500

// ---------------- setup kernels ----------------

__global__ void k_deg(const int* __restrict__ dst, int* __restrict__ deg) {
    int e = blockIdx.x * 256 + threadIdx.x;
    if (e < NE) atomicAdd(&deg[dst[e]], 1);
}

__global__ void k_dinv(const int* __restrict__ deg, float* __restrict__ dinv) {
    int i = blockIdx.x * 256 + threadIdx.x;
    if (i < NN) dinv[i] = rsqrtf((float)deg[i] + 1.0f);
}

// inclusive scan of deg within 256-blocks; rowp[idx+1] = partial inclusive, bsum[b] = block total
__global__ void k_scan1(const int* __restrict__ deg, int* __restrict__ rowp, int* __restrict__ bsum) {
    __shared__ int lds[256];
    int t = threadIdx.x;
    int idx = blockIdx.x * 256 + t;
    int v = (idx < NN) ? deg[idx] : 0;
    lds[t] = v;
    __syncthreads();
    for (int off = 1; off < 256; off <<= 1) {
        int add = (t >= off) ? lds[t - off] : 0;
        __syncthreads();
        lds[t] += add;
        __syncthreads();
    }
    if (idx < NN) rowp[idx + 1] = lds[t];
    if (t == 255) bsum[blockIdx.x] = lds[255];
}

__global__ void k_scan2(int* bsum, int nB) {
    __shared__ int lds[256];
    int t = threadIdx.x;
    lds[t] = (t < nB) ? bsum[t] : 0;
    __syncthreads();
    for (int off = 1; off < 256; off <<= 1) {
        int add = (t >= off) ? lds[t - off] : 0;
        __syncthreads();
        lds[t] += add;
        __syncthreads();
    }
    if (t < nB) bsum[t] = lds[t];
}

__global__ void k_scan3(int* __restrict__ rowp, const int* __restrict__ bsum) {
    int idx = blockIdx.x * 256 + threadIdx.x;
    if (idx == 0) rowp[0] = 0;
    if (blockIdx.x > 0 && idx < NN) rowp[idx + 1] += bsum[blockIdx.x - 1];
}

__global__ void k_fill_init(const int* __restrict__ rowp, int* __restrict__ fill) {
    int i = blockIdx.x * 256 + threadIdx.x;
    if (i < NN) fill[i] = rowp[i];
}

// meta[pos] = {src, bits(dinv[src])} ; dinv[dst] is factored out and applied in k_dual
__global__ void k_csr_fill(const int* __restrict__ srcA, const int* __restrict__ dstA,
                           const float* __restrict__ dinv,
                           int* __restrict__ fill, int2* __restrict__ meta) {
    int e = blockIdx.x * 256 + threadIdx.x;
    if (e < NE) {
        int s = srcA[e], d = dstA[e];
        int pos = atomicAdd(&fill[d], 1);
        int2 m;
        m.x = s;
        m.y = __float_as_int(dinv[s]);
        meta[pos] = m;
    }
}

// ---------------- compute kernels ----------------

// pe = RWPE @ W_rw + b_rw ; h = x + pe   (4 nodes per 256-block)
__global__ void k_pe(const float* __restrict__ x, const float* __restrict__ rwpe,
                     const float* __restrict__ Wrw, const float* __restrict__ brw,
                     float* __restrict__ pe, float* __restrict__ h) {
    __shared__ float Wl[PD * FD];
    __shared__ float rows[4 * PD];
    int t = threadIdx.x;
    int nodeBase = blockIdx.x * 4;
    for (int i = t; i < PD * FD; i += 256) Wl[i] = Wrw[i];
    if (t < 4 * PD) {
        int n = nodeBase + t / PD;
        rows[t] = (n < NN) ? rwpe[n * PD + (t % PD)] : 0.f;
    }
    __syncthreads();
    int f = t & 63, sl = t >> 6;
    int node = nodeBase + sl;
    if (node < NN) {
        float acc = brw[f];
        #pragma unroll
        for (int k = 0; k < PD; k++) acc += rows[sl * PD + k] * Wl[k * FD + f];
        pe[node * FD + f] = acc;
        h[node * FD + f] = x[node * FD + f] + acc;
    }
}

// Fused dual GCN conv (linearity: agg then GEMM):
//   oh = [relu]( aggn(hs_in) @ Wc + bc )
//   if !FINAL:  op = relu( aggn(pe_in) @ Wp + bp );  pe_out = op;  hs_out = oh + op
//   if FINAL:   hs_out = oh  (no relu)
// aggn(a)[i] = dinv_i * sum_e dinv_s a[s] + dinv_i^2 a[i]
// 16 nodes per 256-thread block (NN % 16 == 0), 16 lanes x float4 per node row.
template <bool FINAL>
__global__ __launch_bounds__(256) void k_dual(
    const float* __restrict__ hs_in, const float* __restrict__ pe_in,
    const float* __restrict__ dinv, const int* __restrict__ rowp,
    const int2* __restrict__ meta,
    const float* __restrict__ Wc, const float* __restrict__ bc,
    const float* __restrict__ Wp, const float* __restrict__ bp,
    float* __restrict__ hs_out, float* __restrict__ pe_out)
{
    __shared__ float Wl[64 * 64];       // 16 KB, restaged Wc -> Wp
    __shared__ float aggH[16 * 68];
    __shared__ float aggP[16 * 68];
    int t = threadIdx.x;

    // stage Wc (1024 float4s, 4 per thread)
    {
        const float4* W4 = reinterpret_cast<const float4*>(Wc);
        float4* Wl4 = reinterpret_cast<float4*>(Wl);
        #pragma unroll
        for (int i = 0; i < 4; i++) Wl4[t + 256 * i] = W4[t + 256 * i];
    }

    int l = t & 15;           // float4 chunk within row
    int sl = t >> 4;          // node slot 0..15
    int node = blockIdx.x * 16 + sl;

    float4 aH = make_float4(0.f, 0.f, 0.f, 0.f);
    float4 aP = make_float4(0.f, 0.f, 0.f, 0.f);
    int e0 = rowp[node], e1 = rowp[node + 1];
    int e = e0;
    for (; e + 4 <= e1; e += 4) {
        int2 m0 = meta[e + 0];
        int2 m1 = meta[e + 1];
        int2 m2 = meta[e + 2];
        int2 m3 = meta[e + 3];
        size_t o0 = (size_t)m0.x * 64 + l * 4;
        size_t o1 = (size_t)m1.x * 64 + l * 4;
        size_t o2 = (size_t)m2.x * 64 + l * 4;
        size_t o3 = (size_t)m3.x * 64 + l * 4;
        float4 h0v = *reinterpret_cast<const float4*>(hs_in + o0);
        float4 h1v = *reinterpret_cast<const float4*>(hs_in + o1);
        float4 h2v = *reinterpret_cast<const float4*>(hs_in + o2);
        float4 h3v = *reinterpret_cast<const float4*>(hs_in + o3);
        float4 p0v, p1v, p2v, p3v;
        if (!FINAL) {
            p0v = *reinterpret_cast<const float4*>(pe_in + o0);
            p1v = *reinterpret_cast<const float4*>(pe_in + o1);
            p2v = *reinterpret_cast<const float4*>(pe_in + o2);
            p3v = *reinterpret_cast<const float4*>(pe_in + o3);
        }
        float w0 = __int_as_float(m0.y), w1 = __int_as_float(m1.y);
        float w2 = __int_as_float(m2.y), w3 = __int_as_float(m3.y);
        aH.x += w0 * h0v.x; aH.y += w0 * h0v.y; aH.z += w0 * h0v.z; aH.w += w0 * h0v.w;
        aH.x += w1 * h1v.x; aH.y += w1 * h1v.y; aH.z += w1 * h1v.z; aH.w += w1 * h1v.w;
        aH.x += w2 * h2v.x; aH.y += w2 * h2v.y; aH.z += w2 * h2v.z; aH.w += w2 * h2v.w;
        aH.x += w3 * h3v.x; aH.y += w3 * h3v.y; aH.z += w3 * h3v.z; aH.w += w3 * h3v.w;
        if (!FINAL) {
            aP.x += w0 * p0v.x; aP.y += w0 * p0v.y; aP.z += w0 * p0v.z; aP.w += w0 * p0v.w;
            aP.x += w1 * p1v.x; aP.y += w1 * p1v.y; aP.z += w1 * p1v.z; aP.w += w1 * p1v.w;
            aP.x += w2 * p2v.x; aP.y += w2 * p2v.y; aP.z += w2 * p2v.z; aP.w += w2 * p2v.w;
            aP.x += w3 * p3v.x; aP.y += w3 * p3v.y; aP.z += w3 * p3v.z; aP.w += w3 * p3v.w;
        }
    }
    for (; e < e1; ++e) {
        int2 m = meta[e];
        size_t o = (size_t)m.x * 64 + l * 4;
        float w = __int_as_float(m.y);
        float4 hv = *reinterpret_cast<const float4*>(hs_in + o);
        aH.x += w * hv.x; aH.y += w * hv.y; aH.z += w * hv.z; aH.w += w * hv.w;
        if (!FINAL) {
            float4 pv = *reinterpret_cast<const float4*>(pe_in + o);
            aP.x += w * pv.x; aP.y += w * pv.y; aP.z += w * pv.z; aP.w += w * pv.w;
        }
    }
    {
        float dd = dinv[node];
        float4 sh = *reinterpret_cast<const float4*>(hs_in + (size_t)node * 64 + l * 4);
        float4 v;
        v.x = dd * aH.x + dd * dd * sh.x;
        v.y = dd * aH.y + dd * dd * sh.y;
        v.z = dd * aH.z + dd * dd * sh.z;
        v.w = dd * aH.w + dd * dd * sh.w;
        *reinterpret_cast<float4*>(&aggH[sl * 68 + l * 4]) = v;
        if (!FINAL) {
            float4 sp = *reinterpret_cast<const float4*>(pe_in + (size_t)node * 64 + l * 4);
            float4 u;
            u.x = dd * aP.x + dd * dd * sp.x;
            u.y = dd * aP.y + dd * dd * sp.y;
            u.z = dd * aP.z + dd * dd * sp.z;
            u.w = dd * aP.w + dd * dd * sp.w;
            *reinterpret_cast<float4*>(&aggP[sl * 68 + l * 4]) = u;
        }
    }
    __syncthreads();

    // GEMM-h: oh = aggH @ Wc + bc
    int c = t & 15;
    int sl2 = t >> 4;
    int onode = blockIdx.x * 16 + sl2;
    float4 oh = *reinterpret_cast<const float4*>(bc + c * 4);
    {
        const float* arow = &aggH[sl2 * 68];
        #pragma unroll 16
        for (int k = 0; k < 64; k++) {
            float av = arow[k];
            float4 wv = *reinterpret_cast<const float4*>(&Wl[k * 64 + c * 4]);
            oh.x += av * wv.x; oh.y += av * wv.y; oh.z += av * wv.z; oh.w += av * wv.w;
        }
    }
    if (FINAL) {
        *reinterpret_cast<float4*>(hs_out + (size_t)onode * 64 + c * 4) = oh;
        return;
    }
    oh.x = fmaxf(oh.x, 0.f); oh.y = fmaxf(oh.y, 0.f);
    oh.z = fmaxf(oh.z, 0.f); oh.w = fmaxf(oh.w, 0.f);

    __syncthreads();   // everyone done reading Wc
    // restage Wp over Wl
    {
        const float4* W4 = reinterpret_cast<const float4*>(Wp);
        float4* Wl4 = reinterpret_cast<float4*>(Wl);
        #pragma unroll
        for (int i = 0; i < 4; i++) Wl4[t + 256 * i] = W4[t + 256 * i];
    }
    __syncthreads();

    // GEMM-p: op = relu(aggP @ Wp + bp)
    float4 op = *reinterpret_cast<const float4*>(bp + c * 4);
    {
        const float* arow = &aggP[sl2 * 68];
        #pragma unroll 16
        for (int k = 0; k < 64; k++) {
            float av = arow[k];
            float4 wv = *reinterpret_cast<const float4*>(&Wl[k * 64 + c * 4]);
            op.x += av * wv.x; op.y += av * wv.y; op.z += av * wv.z; op.w += av * wv.w;
        }
    }
    op.x = fmaxf(op.x, 0.f); op.y = fmaxf(op.y, 0.f);
    op.z = fmaxf(op.z, 0.f); op.w = fmaxf(op.w, 0.f);

    *reinterpret_cast<float4*>(pe_out + (size_t)onode * 64 + c * 4) = op;
    float4 sv;
    sv.x = oh.x + op.x; sv.y = oh.y + op.y; sv.z = oh.z + op.z; sv.w = oh.w + op.w;
    *reinterpret_cast<float4*>(hs_out + (size_t)onode * 64 + c * 4) = sv;
}

// ---------------- batchnorm + pool ----------------

__global__ void k_bnstats(const float* __restrict__ h, float* __restrict__ stats) {
    __shared__ float s1[256], s2[256];
    int t = threadIdx.x;
    int f = t & 63, sl = t >> 6;
    float a = 0.f, b = 0.f;
    for (int node = blockIdx.x * 4 + sl; node < NN; node += gridDim.x * 4) {
        float v = h[node * 64 + f];
        a += v;
        b += v * v;
    }
    s1[t] = a;
    s2[t] = b;
    __syncthreads();
    if (t < 64) {
        a = s1[t] + s1[t + 64] + s1[t + 128] + s1[t + 192];
        b = s2[t] + s2[t + 64] + s2[t + 128] + s2[t + 192];
        atomicAdd(&stats[t], a);
        atomicAdd(&stats[64 + t], b);
    }
}

__global__ void k_bnfinal(float* stats) {
    int f = threadIdx.x;
    if (f < 64) {
        float mu = stats[f] / (float)NN;
        float var = stats[64 + f] / (float)NN - mu * mu;
        stats[f] = mu;
        stats[64 + f] = rsqrtf(var + 1e-5f);
    }
}

__global__ void k_pool(const float* __restrict__ h, const float* __restrict__ stats,
                       const float* __restrict__ gamma, const float* __restrict__ beta,
                       const int* __restrict__ ptr, float* __restrict__ out) {
    int g = blockIdx.x;
    int f = threadIdx.x;
    int s = ptr[g], e = ptr[g + 1];
    float mu = stats[f], rstd = stats[64 + f], ga = gamma[f], be = beta[f];
    float acc = 0.f;
    for (int n = s; n < e; n++) {
        float v = (h[n * 64 + f] - mu) * rstd * ga + be;
        acc += fmaxf(v, 0.f);
    }
    out[g * 64 + f] = acc / (float)(e - s);
}

// ---------------- launch ----------------

extern "C" void kernel_launch(void* const* d_in, const int* in_sizes, int n_in,
                              void* d_out, int out_size, void* d_ws, size_t ws_size,
                              hipStream_t stream) {
    const float* x    = (const float*)d_in[0];
    const float* rwpe = (const float*)d_in[1];
    const float* Wrw  = (const float*)d_in[2];
    const float* brw  = (const float*)d_in[3];
    const float *Wc[5], *bc[5], *Wp[5], *bp[5];
    for (int i = 0; i < 5; i++) {
        Wc[i] = (const float*)d_in[4 + 4 * i];
        bc[i] = (const float*)d_in[5 + 4 * i];
        Wp[i] = (const float*)d_in[6 + 4 * i];
        bp[i] = (const float*)d_in[7 + 4 * i];
    }
    const float* gamma = (const float*)d_in[24];
    const float* beta  = (const float*)d_in[25];
    const int* ei  = (const int*)d_in[26];
    const int* ptr = (const int*)d_in[27];
    float* out = (float*)d_out;

    // workspace layout (256B aligned)
    char* wsp = (char*)d_ws;
    auto alloc = [&](size_t bytes) { void* p = (void*)wsp; wsp += ((bytes + 255) / 256) * 256; return p; };
    int*   deg   = (int*)alloc(NN * 4);
    int*   rowp  = (int*)alloc((NN + 1) * 4);
    int*   fill  = (int*)alloc(NN * 4);
    int2*  meta  = (int2*)alloc((size_t)NE * 8);
    float* dinv  = (float*)alloc(NN * 4);
    float* bufA  = (float*)alloc((size_t)NN * 64 * 4);   // hs ping (init h0 = x+pe)
    float* bufB  = (float*)alloc((size_t)NN * 64 * 4);   // pe ping (init pe0)
    float* bufC  = (float*)alloc((size_t)NN * 64 * 4);   // hs pong
    float* bufD  = (float*)alloc((size_t)NN * 64 * 4);   // pe pong
    float* stats = (float*)alloc(512);
    int*   bsum  = (int*)alloc(256 * 4);

    hipMemsetAsync(deg, 0, NN * 4, stream);
    hipMemsetAsync(stats, 0, 512, stream);

    const int* srcA = ei;
    const int* dstA = ei + NE;

    dim3 b256(256);
    int gE = (NE + 255) / 256;
    int gN = (NN + 255) / 256;       // 196 blocks (<= 256, fits scan2)
    int gNode16 = NN / 16;           // 3125 (exact)

    k_deg<<<gE, b256, 0, stream>>>(dstA, deg);
    k_dinv<<<gN, b256, 0, stream>>>(deg, dinv);
    k_scan1<<<gN, b256, 0, stream>>>(deg, rowp, bsum);
    k_scan2<<<1, b256, 0, stream>>>(bsum, gN);
    k_scan3<<<gN, b256, 0, stream>>>(rowp, bsum);
    k_fill_init<<<gN, b256, 0, stream>>>(rowp, fill);
    k_csr_fill<<<gE, b256, 0, stream>>>(srcA, dstA, dinv, fill, meta);

    k_pe<<<(NN + 3) / 4, b256, 0, stream>>>(x, rwpe, Wrw, brw, bufB, bufA);

    // K0: conv1(Wc1) on bufA  +  pe-conv(Wp1) on bufB  -> hs=bufC, pe=bufD
    k_dual<false><<<gNode16, b256, 0, stream>>>(
        bufA, bufB, dinv, rowp, meta,
        Wc[0], bc[0], Wp[0], bp[0], bufC, bufD);
    // K1
    k_dual<false><<<gNode16, b256, 0, stream>>>(
        bufC, bufD, dinv, rowp, meta,
        Wc[1], bc[1], Wp[1], bp[1], bufA, bufB);
    // K2
    k_dual<false><<<gNode16, b256, 0, stream>>>(
        bufA, bufB, dinv, rowp, meta,
        Wc[2], bc[2], Wp[2], bp[2], bufC, bufD);
    // K3
    k_dual<false><<<gNode16, b256, 0, stream>>>(
        bufC, bufD, dinv, rowp, meta,
        Wc[3], bc[3], Wp[3], bp[3], bufA, bufB);
    // K4: final conv(Wc5) on bufA -> h5 = bufC (no relu)
    k_dual<true><<<gNode16, b256, 0, stream>>>(
        bufA, nullptr, dinv, rowp, meta,
        Wc[4], bc[4], nullptr, nullptr, bufC, nullptr);

    k_bnstats<<<256, b256, 0, stream>>>(bufC, stats);
    k_bnfinal<<<1, 64, 0, stream>>>(stats);
    k_pool<<<NG, 64, 0, stream>>>(bufC, stats, gamma, beta, ptr, out);
}

// Round 6
// 371.243 us; speedup vs baseline: 1.9563x; 1.3099x over previous
//
#include <hip/hip_runtime.h>
#include <hip/hip_fp16.h>

#define NN 50000
#define NE 800000
#define FD 64
#define PD 20
#define NG 500

// ---------------- setup kernels ----------------

__global__ void k_deg(const int* __restrict__ dst, int* __restrict__ deg) {
    int e = blockIdx.x * 256 + threadIdx.x;
    if (e < NE) atomicAdd(&deg[dst[e]], 1);
}

__global__ void k_dinv(const int* __restrict__ deg, float* __restrict__ dinv) {
    int i = blockIdx.x * 256 + threadIdx.x;
    if (i < NN) dinv[i] = rsqrtf((float)deg[i] + 1.0f);
}

__global__ void k_scan1(const int* __restrict__ deg, int* __restrict__ rowp, int* __restrict__ bsum) {
    __shared__ int lds[256];
    int t = threadIdx.x;
    int idx = blockIdx.x * 256 + t;
    int v = (idx < NN) ? deg[idx] : 0;
    lds[t] = v;
    __syncthreads();
    for (int off = 1; off < 256; off <<= 1) {
        int add = (t >= off) ? lds[t - off] : 0;
        __syncthreads();
        lds[t] += add;
        __syncthreads();
    }
    if (idx < NN) rowp[idx + 1] = lds[t];
    if (t == 255) bsum[blockIdx.x] = lds[255];
}

__global__ void k_scan2(int* bsum, int nB) {
    __shared__ int lds[256];
    int t = threadIdx.x;
    lds[t] = (t < nB) ? bsum[t] : 0;
    __syncthreads();
    for (int off = 1; off < 256; off <<= 1) {
        int add = (t >= off) ? lds[t - off] : 0;
        __syncthreads();
        lds[t] += add;
        __syncthreads();
    }
    if (t < nB) bsum[t] = lds[t];
}

__global__ void k_scan3(int* __restrict__ rowp, const int* __restrict__ bsum) {
    int idx = blockIdx.x * 256 + threadIdx.x;
    if (idx == 0) rowp[0] = 0;
    if (blockIdx.x > 0 && idx < NN) rowp[idx + 1] += bsum[blockIdx.x - 1];
}

__global__ void k_fill_init(const int* __restrict__ rowp, int* __restrict__ fill) {
    int i = blockIdx.x * 256 + threadIdx.x;
    if (i < NN) fill[i] = rowp[i];
}

__global__ void k_csr_fill(const int* __restrict__ srcA, const int* __restrict__ dstA,
                           const float* __restrict__ dinv,
                           int* __restrict__ fill, int2* __restrict__ meta) {
    int e = blockIdx.x * 256 + threadIdx.x;
    if (e < NE) {
        int s = srcA[e], d = dstA[e];
        int pos = atomicAdd(&fill[d], 1);
        int2 m;
        m.x = s;
        m.y = __float_as_int(dinv[s]);
        meta[pos] = m;
    }
}

// ---------------- compute kernels ----------------

// pe = RWPE @ W_rw + b_rw ; writes interleaved fp16 row: [hs = x+pe | pe]
__global__ void k_pe(const float* __restrict__ x, const float* __restrict__ rwpe,
                     const float* __restrict__ Wrw, const float* __restrict__ brw,
                     __half* __restrict__ outI) {
    __shared__ float Wl[PD * FD];
    __shared__ float rows[4 * PD];
    int t = threadIdx.x;
    int nodeBase = blockIdx.x * 4;
    for (int i = t; i < PD * FD; i += 256) Wl[i] = Wrw[i];
    if (t < 4 * PD) {
        int n = nodeBase + t / PD;
        rows[t] = (n < NN) ? rwpe[n * PD + (t % PD)] : 0.f;
    }
    __syncthreads();
    int f = t & 63, sl = t >> 6;
    int node = nodeBase + sl;
    if (node < NN) {
        float acc = brw[f];
        #pragma unroll
        for (int k = 0; k < PD; k++) acc += rows[sl * PD + k] * Wl[k * FD + f];
        outI[(size_t)node * 128 + f]      = __float2half_rn(x[node * FD + f] + acc);
        outI[(size_t)node * 128 + 64 + f] = __float2half_rn(acc);
    }
}

__device__ inline void acc8(float* acc, uint4 v, float w) {
    const __half2* h = reinterpret_cast<const __half2*>(&v);
    float2 f0 = __half22float2(h[0]);
    float2 f1 = __half22float2(h[1]);
    float2 f2 = __half22float2(h[2]);
    float2 f3 = __half22float2(h[3]);
    acc[0] += w * f0.x; acc[1] += w * f0.y;
    acc[2] += w * f1.x; acc[3] += w * f1.y;
    acc[4] += w * f2.x; acc[5] += w * f2.y;
    acc[6] += w * f3.x; acc[7] += w * f3.y;
}

__device__ inline void acc4(float* acc, uint2 v, float w) {
    const __half2* h = reinterpret_cast<const __half2*>(&v);
    float2 f0 = __half22float2(h[0]);
    float2 f1 = __half22float2(h[1]);
    acc[0] += w * f0.x; acc[1] += w * f0.y;
    acc[2] += w * f1.x; acc[3] += w * f1.y;
}

// Fused dual GCN conv on interleaved fp16 state rows [hs(64)|pe(64)].
//   oh = relu( aggn(hs) @ Wc + bc )           (no relu if FINAL)
//   op = relu( aggn(pe) @ Wp + bp )           (non-final only)
//   out row = [oh+op | op] (fp16)  ;  FINAL: foutF = oh (fp32 planar)
// aggn(a)[i] = dinv_i * sum_e dinv_s a[s] + dinv_i^2 a[i]
// 16 nodes per 256-thread block; lanes 0-7 cover hs feats, 8-15 pe feats.
template <bool FINAL>
__global__ __launch_bounds__(256) void k_dual(
    const __half* __restrict__ in,
    const float* __restrict__ dinv, const int* __restrict__ rowp,
    const int2* __restrict__ meta,
    const float* __restrict__ Wc, const float* __restrict__ bc,
    const float* __restrict__ Wp, const float* __restrict__ bp,
    __half* __restrict__ out, int write_pe,
    float* __restrict__ foutF)
{
    __shared__ float Wl[64 * 64];
    __shared__ float aggH[16 * 68];
    __shared__ float aggP[16 * 68];
    int t = threadIdx.x;

    // stage Wc
    {
        const float4* W4 = reinterpret_cast<const float4*>(Wc);
        float4* Wl4 = reinterpret_cast<float4*>(Wl);
        #pragma unroll
        for (int i = 0; i < 4; i++) Wl4[t + 256 * i] = W4[t + 256 * i];
    }

    int l = t & 15;
    int sl = t >> 4;
    int node = blockIdx.x * 16 + sl;
    int e0 = rowp[node], e1 = rowp[node + 1];
    float dd = dinv[node];

    if (!FINAL) {
        const uint4* base = reinterpret_cast<const uint4*>(in);   // row = 16 uint4
        float acc[8] = {0, 0, 0, 0, 0, 0, 0, 0};
        int e = e0;
        for (; e + 4 <= e1; e += 4) {
            int2 m0 = meta[e + 0];
            int2 m1 = meta[e + 1];
            int2 m2 = meta[e + 2];
            int2 m3 = meta[e + 3];
            uint4 v0 = base[(size_t)m0.x * 16 + l];
            uint4 v1 = base[(size_t)m1.x * 16 + l];
            uint4 v2 = base[(size_t)m2.x * 16 + l];
            uint4 v3 = base[(size_t)m3.x * 16 + l];
            acc8(acc, v0, __int_as_float(m0.y));
            acc8(acc, v1, __int_as_float(m1.y));
            acc8(acc, v2, __int_as_float(m2.y));
            acc8(acc, v3, __int_as_float(m3.y));
        }
        for (; e < e1; ++e) {
            int2 m = meta[e];
            acc8(acc, base[(size_t)m.x * 16 + l], __int_as_float(m.y));
        }
        float s[8];
        {
            uint4 sv = base[(size_t)node * 16 + l];
            const __half2* h = reinterpret_cast<const __half2*>(&sv);
            float2 f0 = __half22float2(h[0]);
            float2 f1 = __half22float2(h[1]);
            float2 f2 = __half22float2(h[2]);
            float2 f3 = __half22float2(h[3]);
            s[0] = f0.x; s[1] = f0.y; s[2] = f1.x; s[3] = f1.y;
            s[4] = f2.x; s[5] = f2.y; s[6] = f3.x; s[7] = f3.y;
        }
        float* dst = (l < 8) ? &aggH[sl * 68 + l * 8] : &aggP[sl * 68 + (l - 8) * 8];
        float4* d4 = reinterpret_cast<float4*>(dst);
        d4[0] = make_float4(dd * acc[0] + dd * dd * s[0],
                            dd * acc[1] + dd * dd * s[1],
                            dd * acc[2] + dd * dd * s[2],
                            dd * acc[3] + dd * dd * s[3]);
        d4[1] = make_float4(dd * acc[4] + dd * dd * s[4],
                            dd * acc[5] + dd * dd * s[5],
                            dd * acc[6] + dd * dd * s[6],
                            dd * acc[7] + dd * dd * s[7]);
    } else {
        const uint2* base2 = reinterpret_cast<const uint2*>(in);  // row = 32 uint2, hs = first 16
        float acc[4] = {0, 0, 0, 0};
        int e = e0;
        for (; e + 4 <= e1; e += 4) {
            int2 m0 = meta[e + 0];
            int2 m1 = meta[e + 1];
            int2 m2 = meta[e + 2];
            int2 m3 = meta[e + 3];
            uint2 v0 = base2[(size_t)m0.x * 32 + l];
            uint2 v1 = base2[(size_t)m1.x * 32 + l];
            uint2 v2 = base2[(size_t)m2.x * 32 + l];
            uint2 v3 = base2[(size_t)m3.x * 32 + l];
            acc4(acc, v0, __int_as_float(m0.y));
            acc4(acc, v1, __int_as_float(m1.y));
            acc4(acc, v2, __int_as_float(m2.y));
            acc4(acc, v3, __int_as_float(m3.y));
        }
        for (; e < e1; ++e) {
            int2 m = meta[e];
            acc4(acc, base2[(size_t)m.x * 32 + l], __int_as_float(m.y));
        }
        float s[4];
        {
            uint2 sv = base2[(size_t)node * 32 + l];
            const __half2* h = reinterpret_cast<const __half2*>(&sv);
            float2 f0 = __half22float2(h[0]);
            float2 f1 = __half22float2(h[1]);
            s[0] = f0.x; s[1] = f0.y; s[2] = f1.x; s[3] = f1.y;
        }
        float4* d4 = reinterpret_cast<float4*>(&aggH[sl * 68 + l * 4]);
        d4[0] = make_float4(dd * acc[0] + dd * dd * s[0],
                            dd * acc[1] + dd * dd * s[1],
                            dd * acc[2] + dd * dd * s[2],
                            dd * acc[3] + dd * dd * s[3]);
    }
    __syncthreads();

    // GEMM-h: oh = aggH @ Wc + bc
    int c = t & 15;
    int sl2 = t >> 4;
    int onode = blockIdx.x * 16 + sl2;
    float4 oh = *reinterpret_cast<const float4*>(bc + c * 4);
    {
        const float* arow = &aggH[sl2 * 68];
        #pragma unroll 16
        for (int k = 0; k < 64; k++) {
            float av = arow[k];
            float4 wv = *reinterpret_cast<const float4*>(&Wl[k * 64 + c * 4]);
            oh.x += av * wv.x; oh.y += av * wv.y; oh.z += av * wv.z; oh.w += av * wv.w;
        }
    }
    if (FINAL) {
        *reinterpret_cast<float4*>(foutF + (size_t)onode * 64 + c * 4) = oh;
        return;
    }
    oh.x = fmaxf(oh.x, 0.f); oh.y = fmaxf(oh.y, 0.f);
    oh.z = fmaxf(oh.z, 0.f); oh.w = fmaxf(oh.w, 0.f);

    __syncthreads();
    // restage Wp
    {
        const float4* W4 = reinterpret_cast<const float4*>(Wp);
        float4* Wl4 = reinterpret_cast<float4*>(Wl);
        #pragma unroll
        for (int i = 0; i < 4; i++) Wl4[t + 256 * i] = W4[t + 256 * i];
    }
    __syncthreads();

    // GEMM-p: op = relu(aggP @ Wp + bp)
    float4 op = *reinterpret_cast<const float4*>(bp + c * 4);
    {
        const float* arow = &aggP[sl2 * 68];
        #pragma unroll 16
        for (int k = 0; k < 64; k++) {
            float av = arow[k];
            float4 wv = *reinterpret_cast<const float4*>(&Wl[k * 64 + c * 4]);
            op.x += av * wv.x; op.y += av * wv.y; op.z += av * wv.z; op.w += av * wv.w;
        }
    }
    op.x = fmaxf(op.x, 0.f); op.y = fmaxf(op.y, 0.f);
    op.z = fmaxf(op.z, 0.f); op.w = fmaxf(op.w, 0.f);

    // pack + store: hs = oh+op at uint2 slot [node*32 + c], pe = op at [node*32 + 16 + c]
    uint2* out2 = reinterpret_cast<uint2*>(out);
    {
        __half2 a = __floats2half2_rn(oh.x + op.x, oh.y + op.y);
        __half2 b = __floats2half2_rn(oh.z + op.z, oh.w + op.w);
        uint2 u;
        u.x = *reinterpret_cast<unsigned int*>(&a);
        u.y = *reinterpret_cast<unsigned int*>(&b);
        out2[(size_t)onode * 32 + c] = u;
    }
    if (write_pe) {
        __half2 a = __floats2half2_rn(op.x, op.y);
        __half2 b = __floats2half2_rn(op.z, op.w);
        uint2 u;
        u.x = *reinterpret_cast<unsigned int*>(&a);
        u.y = *reinterpret_cast<unsigned int*>(&b);
        out2[(size_t)onode * 32 + 16 + c] = u;
    }
}

// ---------------- batchnorm + pool ----------------

__global__ void k_bnstats(const float* __restrict__ h, float* __restrict__ stats) {
    __shared__ float s1[256], s2[256];
    int t = threadIdx.x;
    int f = t & 63, sl = t >> 6;
    float a = 0.f, b = 0.f;
    for (int node = blockIdx.x * 4 + sl; node < NN; node += gridDim.x * 4) {
        float v = h[node * 64 + f];
        a += v;
        b += v * v;
    }
    s1[t] = a;
    s2[t] = b;
    __syncthreads();
    if (t < 64) {
        a = s1[t] + s1[t + 64] + s1[t + 128] + s1[t + 192];
        b = s2[t] + s2[t + 64] + s2[t + 128] + s2[t + 192];
        atomicAdd(&stats[t], a);
        atomicAdd(&stats[64 + t], b);
    }
}

__global__ void k_bnfinal(float* stats) {
    int f = threadIdx.x;
    if (f < 64) {
        float mu = stats[f] / (float)NN;
        float var = stats[64 + f] / (float)NN - mu * mu;
        stats[f] = mu;
        stats[64 + f] = rsqrtf(var + 1e-5f);
    }
}

__global__ void k_pool(const float* __restrict__ h, const float* __restrict__ stats,
                       const float* __restrict__ gamma, const float* __restrict__ beta,
                       const int* __restrict__ ptr, float* __restrict__ out) {
    int g = blockIdx.x;
    int f = threadIdx.x;
    int s = ptr[g], e = ptr[g + 1];
    float mu = stats[f], rstd = stats[64 + f], ga = gamma[f], be = beta[f];
    float acc = 0.f;
    for (int n = s; n < e; n++) {
        float v = (h[n * 64 + f] - mu) * rstd * ga + be;
        acc += fmaxf(v, 0.f);
    }
    out[g * 64 + f] = acc / (float)(e - s);
}

// ---------------- launch ----------------

extern "C" void kernel_launch(void* const* d_in, const int* in_sizes, int n_in,
                              void* d_out, int out_size, void* d_ws, size_t ws_size,
                              hipStream_t stream) {
    const float* x    = (const float*)d_in[0];
    const float* rwpe = (const float*)d_in[1];
    const float* Wrw  = (const float*)d_in[2];
    const float* brw  = (const float*)d_in[3];
    const float *Wc[5], *bc[5], *Wp[5], *bp[5];
    for (int i = 0; i < 5; i++) {
        Wc[i] = (const float*)d_in[4 + 4 * i];
        bc[i] = (const float*)d_in[5 + 4 * i];
        Wp[i] = (const float*)d_in[6 + 4 * i];
        bp[i] = (const float*)d_in[7 + 4 * i];
    }
    const float* gamma = (const float*)d_in[24];
    const float* beta  = (const float*)d_in[25];
    const int* ei  = (const int*)d_in[26];
    const int* ptr = (const int*)d_in[27];
    float* out = (float*)d_out;

    char* wsp = (char*)d_ws;
    auto alloc = [&](size_t bytes) { void* p = (void*)wsp; wsp += ((bytes + 255) / 256) * 256; return p; };
    int*    deg   = (int*)alloc(NN * 4);
    int*    rowp  = (int*)alloc((NN + 1) * 4);
    int*    fill  = (int*)alloc(NN * 4);
    int2*   meta  = (int2*)alloc((size_t)NE * 8);
    float*  dinv  = (float*)alloc(NN * 4);
    __half* bufP  = (__half*)alloc((size_t)NN * 128 * 2);   // interleaved [hs|pe]
    __half* bufQ  = (__half*)alloc((size_t)NN * 128 * 2);
    float*  bufF  = (float*)alloc((size_t)NN * 64 * 4);     // final conv5 out fp32
    float*  stats = (float*)alloc(512);
    int*    bsum  = (int*)alloc(256 * 4);

    hipMemsetAsync(deg, 0, NN * 4, stream);
    hipMemsetAsync(stats, 0, 512, stream);

    const int* srcA = ei;
    const int* dstA = ei + NE;

    dim3 b256(256);
    int gE = (NE + 255) / 256;
    int gN = (NN + 255) / 256;
    int gNode16 = NN / 16;           // 3125 (exact)

    k_deg<<<gE, b256, 0, stream>>>(dstA, deg);
    k_dinv<<<gN, b256, 0, stream>>>(deg, dinv);
    k_scan1<<<gN, b256, 0, stream>>>(deg, rowp, bsum);
    k_scan2<<<1, b256, 0, stream>>>(bsum, gN);
    k_scan3<<<gN, b256, 0, stream>>>(rowp, bsum);
    k_fill_init<<<gN, b256, 0, stream>>>(rowp, fill);
    k_csr_fill<<<gE, b256, 0, stream>>>(srcA, dstA, dinv, fill, meta);

    k_pe<<<(NN + 3) / 4, b256, 0, stream>>>(x, rwpe, Wrw, brw, bufP);

    // K0..K3: dual convs; K3 skips dead pe write
    k_dual<false><<<gNode16, b256, 0, stream>>>(
        bufP, dinv, rowp, meta, Wc[0], bc[0], Wp[0], bp[0], bufQ, 1, nullptr);
    k_dual<false><<<gNode16, b256, 0, stream>>>(
        bufQ, dinv, rowp, meta, Wc[1], bc[1], Wp[1], bp[1], bufP, 1, nullptr);
    k_dual<false><<<gNode16, b256, 0, stream>>>(
        bufP, dinv, rowp, meta, Wc[2], bc[2], Wp[2], bp[2], bufQ, 1, nullptr);
    k_dual<false><<<gNode16, b256, 0, stream>>>(
        bufQ, dinv, rowp, meta, Wc[3], bc[3], Wp[3], bp[3], bufP, 0, nullptr);
    // K4: final conv (hs only) -> fp32
    k_dual<true><<<gNode16, b256, 0, stream>>>(
        bufP, dinv, rowp, meta, Wc[4], bc[4], nullptr, nullptr, nullptr, 0, bufF);

    k_bnstats<<<256, b256, 0, stream>>>(bufF, stats);
    k_bnfinal<<<1, 64, 0, stream>>>(stats);
    k_pool<<<NG, 64, 0, stream>>>(bufF, stats, gamma, beta, ptr, out);
}

// Round 7
// 363.611 us; speedup vs baseline: 1.9974x; 1.0210x over previous
//
#include <hip/hip_runtime.h>
#include <hip/hip_fp16.h>

#define NN 50000
#define NE 800000
#define FD 64
#define PD 20
#define NG 500
#define NXCD 8
#define DRANGE 6250            // NN / NXCD
#define CHUNK_E 2048

// ---------------- setup kernels ----------------

__global__ void k_deg(const int* __restrict__ dst, int* __restrict__ deg) {
    int e = blockIdx.x * 256 + threadIdx.x;
    if (e < NE) atomicAdd(&deg[dst[e]], 1);
}

__global__ void k_dinv(const int* __restrict__ deg, float* __restrict__ dinv) {
    int i = blockIdx.x * 256 + threadIdx.x;
    if (i < NN) dinv[i] = rsqrtf((float)deg[i] + 1.0f);
}

__global__ void k_scan1(const int* __restrict__ deg, int* __restrict__ rowp, int* __restrict__ bsum) {
    __shared__ int lds[256];
    int t = threadIdx.x;
    int idx = blockIdx.x * 256 + t;
    int v = (idx < NN) ? deg[idx] : 0;
    lds[t] = v;
    __syncthreads();
    for (int off = 1; off < 256; off <<= 1) {
        int add = (t >= off) ? lds[t - off] : 0;
        __syncthreads();
        lds[t] += add;
        __syncthreads();
    }
    if (idx < NN) rowp[idx + 1] = lds[t];
    if (t == 255) bsum[blockIdx.x] = lds[255];
}

__global__ void k_scan2(int* bsum, int nB) {
    __shared__ int lds[256];
    int t = threadIdx.x;
    lds[t] = (t < nB) ? bsum[t] : 0;
    __syncthreads();
    for (int off = 1; off < 256; off <<= 1) {
        int add = (t >= off) ? lds[t - off] : 0;
        __syncthreads();
        lds[t] += add;
        __syncthreads();
    }
    if (t < nB) bsum[t] = lds[t];
}

// finalize rowp AND produce fill[] (fill[i] = rowp[i]) in one pass
__global__ void k_scan3(int* __restrict__ rowp, const int* __restrict__ bsum,
                        int* __restrict__ fill) {
    int idx = blockIdx.x * 256 + threadIdx.x;
    if (idx == 0) { rowp[0] = 0; fill[0] = 0; }
    if (idx < NN) {
        int v = rowp[idx + 1];
        if (blockIdx.x > 0) { v += bsum[blockIdx.x - 1]; rowp[idx + 1] = v; }
        if (idx + 1 < NN) fill[idx + 1] = v;
    }
}

// XCD-partitioned CSR fill: block b -> xcd lane (b & 7), edge chunk (b >> 3).
// Only edges with dst in this xcd's range are written, so each meta line is
// dirtied by exactly one XCD's L2 -> no cross-XCD write amplification.
__global__ void k_csr_fill_xcd(const int* __restrict__ srcA, const int* __restrict__ dstA,
                               const float* __restrict__ dinv,
                               int* __restrict__ fill, int2* __restrict__ meta) {
    int xcd = blockIdx.x & 7;
    int chunk = blockIdx.x >> 3;
    int lo = xcd * DRANGE;
    int hi = lo + DRANGE;      // NN divisible by 8
    int base = chunk * CHUNK_E;
    int end = min(base + CHUNK_E, NE);
    for (int i = base + threadIdx.x; i < end; i += 256) {
        int d = dstA[i];
        if (d >= lo && d < hi) {
            int s = srcA[i];
            int pos = atomicAdd(&fill[d], 1);
            int2 m;
            m.x = s;
            m.y = __float_as_int(dinv[s]);
            meta[pos] = m;
        }
    }
}

// ---------------- compute kernels ----------------

// pe = RWPE @ W_rw + b_rw ; writes interleaved fp16 row: [hs = x+pe | pe]
__global__ void k_pe(const float* __restrict__ x, const float* __restrict__ rwpe,
                     const float* __restrict__ Wrw, const float* __restrict__ brw,
                     __half* __restrict__ outI) {
    __shared__ float Wl[PD * FD];
    __shared__ float rows[4 * PD];
    int t = threadIdx.x;
    int nodeBase = blockIdx.x * 4;
    for (int i = t; i < PD * FD; i += 256) Wl[i] = Wrw[i];
    if (t < 4 * PD) {
        int n = nodeBase + t / PD;
        rows[t] = (n < NN) ? rwpe[n * PD + (t % PD)] : 0.f;
    }
    __syncthreads();
    int f = t & 63, sl = t >> 6;
    int node = nodeBase + sl;
    if (node < NN) {
        float acc = brw[f];
        #pragma unroll
        for (int k = 0; k < PD; k++) acc += rows[sl * PD + k] * Wl[k * FD + f];
        outI[(size_t)node * 128 + f]      = __float2half_rn(x[node * FD + f] + acc);
        outI[(size_t)node * 128 + 64 + f] = __float2half_rn(acc);
    }
}

__device__ inline void acc8(float* acc, uint4 v, float w) {
    const __half2* h = reinterpret_cast<const __half2*>(&v);
    float2 f0 = __half22float2(h[0]);
    float2 f1 = __half22float2(h[1]);
    float2 f2 = __half22float2(h[2]);
    float2 f3 = __half22float2(h[3]);
    acc[0] += w * f0.x; acc[1] += w * f0.y;
    acc[2] += w * f1.x; acc[3] += w * f1.y;
    acc[4] += w * f2.x; acc[5] += w * f2.y;
    acc[6] += w * f3.x; acc[7] += w * f3.y;
}

__device__ inline void acc4(float* acc, uint2 v, float w) {
    const __half2* h = reinterpret_cast<const __half2*>(&v);
    float2 f0 = __half22float2(h[0]);
    float2 f1 = __half22float2(h[1]);
    acc[0] += w * f0.x; acc[1] += w * f0.y;
    acc[2] += w * f1.x; acc[3] += w * f1.y;
}

// Fused dual GCN conv on interleaved fp16 state rows [hs(64)|pe(64)].
//   oh = relu( aggn(hs) @ Wc + bc )           (no relu if FINAL)
//   op = relu( aggn(pe) @ Wp + bp )           (non-final only)
//   out row = [oh+op | op] (fp16)  ;  FINAL: foutF = oh (fp32 planar)
// aggn(a)[i] = dinv_i * sum_e dinv_s a[s] + dinv_i^2 a[i]
// 16 nodes per 256-thread block; lanes 0-7 cover hs feats, 8-15 pe feats.
template <bool FINAL>
__global__ __launch_bounds__(256) void k_dual(
    const __half* __restrict__ in,
    const float* __restrict__ dinv, const int* __restrict__ rowp,
    const int2* __restrict__ meta,
    const float* __restrict__ Wc, const float* __restrict__ bc,
    const float* __restrict__ Wp, const float* __restrict__ bp,
    __half* __restrict__ out, int write_pe,
    float* __restrict__ foutF)
{
    __shared__ float Wl[64 * 64];
    __shared__ float aggH[16 * 68];
    __shared__ float aggP[16 * 68];
    int t = threadIdx.x;

    // stage Wc
    {
        const float4* W4 = reinterpret_cast<const float4*>(Wc);
        float4* Wl4 = reinterpret_cast<float4*>(Wl);
        #pragma unroll
        for (int i = 0; i < 4; i++) Wl4[t + 256 * i] = W4[t + 256 * i];
    }

    int l = t & 15;
    int sl = t >> 4;
    int node = blockIdx.x * 16 + sl;
    int e0 = rowp[node], e1 = rowp[node + 1];
    float dd = dinv[node];

    if (!FINAL) {
        const uint4* base = reinterpret_cast<const uint4*>(in);   // row = 16 uint4
        float acc[8] = {0, 0, 0, 0, 0, 0, 0, 0};
        int e = e0;
        for (; e + 8 <= e1; e += 8) {
            int2 m0 = meta[e + 0];
            int2 m1 = meta[e + 1];
            int2 m2 = meta[e + 2];
            int2 m3 = meta[e + 3];
            int2 m4 = meta[e + 4];
            int2 m5 = meta[e + 5];
            int2 m6 = meta[e + 6];
            int2 m7 = meta[e + 7];
            uint4 v0 = base[(size_t)m0.x * 16 + l];
            uint4 v1 = base[(size_t)m1.x * 16 + l];
            uint4 v2 = base[(size_t)m2.x * 16 + l];
            uint4 v3 = base[(size_t)m3.x * 16 + l];
            uint4 v4 = base[(size_t)m4.x * 16 + l];
            uint4 v5 = base[(size_t)m5.x * 16 + l];
            uint4 v6 = base[(size_t)m6.x * 16 + l];
            uint4 v7 = base[(size_t)m7.x * 16 + l];
            acc8(acc, v0, __int_as_float(m0.y));
            acc8(acc, v1, __int_as_float(m1.y));
            acc8(acc, v2, __int_as_float(m2.y));
            acc8(acc, v3, __int_as_float(m3.y));
            acc8(acc, v4, __int_as_float(m4.y));
            acc8(acc, v5, __int_as_float(m5.y));
            acc8(acc, v6, __int_as_float(m6.y));
            acc8(acc, v7, __int_as_float(m7.y));
        }
        for (; e + 4 <= e1; e += 4) {
            int2 m0 = meta[e + 0];
            int2 m1 = meta[e + 1];
            int2 m2 = meta[e + 2];
            int2 m3 = meta[e + 3];
            uint4 v0 = base[(size_t)m0.x * 16 + l];
            uint4 v1 = base[(size_t)m1.x * 16 + l];
            uint4 v2 = base[(size_t)m2.x * 16 + l];
            uint4 v3 = base[(size_t)m3.x * 16 + l];
            acc8(acc, v0, __int_as_float(m0.y));
            acc8(acc, v1, __int_as_float(m1.y));
            acc8(acc, v2, __int_as_float(m2.y));
            acc8(acc, v3, __int_as_float(m3.y));
        }
        for (; e < e1; ++e) {
            int2 m = meta[e];
            acc8(acc, base[(size_t)m.x * 16 + l], __int_as_float(m.y));
        }
        float s[8];
        {
            uint4 sv = base[(size_t)node * 16 + l];
            const __half2* h = reinterpret_cast<const __half2*>(&sv);
            float2 f0 = __half22float2(h[0]);
            float2 f1 = __half22float2(h[1]);
            float2 f2 = __half22float2(h[2]);
            float2 f3 = __half22float2(h[3]);
            s[0] = f0.x; s[1] = f0.y; s[2] = f1.x; s[3] = f1.y;
            s[4] = f2.x; s[5] = f2.y; s[6] = f3.x; s[7] = f3.y;
        }
        float* dst = (l < 8) ? &aggH[sl * 68 + l * 8] : &aggP[sl * 68 + (l - 8) * 8];
        float4* d4 = reinterpret_cast<float4*>(dst);
        d4[0] = make_float4(dd * acc[0] + dd * dd * s[0],
                            dd * acc[1] + dd * dd * s[1],
                            dd * acc[2] + dd * dd * s[2],
                            dd * acc[3] + dd * dd * s[3]);
        d4[1] = make_float4(dd * acc[4] + dd * dd * s[4],
                            dd * acc[5] + dd * dd * s[5],
                            dd * acc[6] + dd * dd * s[6],
                            dd * acc[7] + dd * dd * s[7]);
    } else {
        const uint2* base2 = reinterpret_cast<const uint2*>(in);  // row = 32 uint2, hs = first 16
        float acc[4] = {0, 0, 0, 0};
        int e = e0;
        for (; e + 8 <= e1; e += 8) {
            int2 m0 = meta[e + 0];
            int2 m1 = meta[e + 1];
            int2 m2 = meta[e + 2];
            int2 m3 = meta[e + 3];
            int2 m4 = meta[e + 4];
            int2 m5 = meta[e + 5];
            int2 m6 = meta[e + 6];
            int2 m7 = meta[e + 7];
            uint2 v0 = base2[(size_t)m0.x * 32 + l];
            uint2 v1 = base2[(size_t)m1.x * 32 + l];
            uint2 v2 = base2[(size_t)m2.x * 32 + l];
            uint2 v3 = base2[(size_t)m3.x * 32 + l];
            uint2 v4 = base2[(size_t)m4.x * 32 + l];
            uint2 v5 = base2[(size_t)m5.x * 32 + l];
            uint2 v6 = base2[(size_t)m6.x * 32 + l];
            uint2 v7 = base2[(size_t)m7.x * 32 + l];
            acc4(acc, v0, __int_as_float(m0.y));
            acc4(acc, v1, __int_as_float(m1.y));
            acc4(acc, v2, __int_as_float(m2.y));
            acc4(acc, v3, __int_as_float(m3.y));
            acc4(acc, v4, __int_as_float(m4.y));
            acc4(acc, v5, __int_as_float(m5.y));
            acc4(acc, v6, __int_as_float(m6.y));
            acc4(acc, v7, __int_as_float(m7.y));
        }
        for (; e < e1; ++e) {
            int2 m = meta[e];
            acc4(acc, base2[(size_t)m.x * 32 + l], __int_as_float(m.y));
        }
        float s[4];
        {
            uint2 sv = base2[(size_t)node * 32 + l];
            const __half2* h = reinterpret_cast<const __half2*>(&sv);
            float2 f0 = __half22float2(h[0]);
            float2 f1 = __half22float2(h[1]);
            s[0] = f0.x; s[1] = f0.y; s[2] = f1.x; s[3] = f1.y;
        }
        float4* d4 = reinterpret_cast<float4*>(&aggH[sl * 68 + l * 4]);
        d4[0] = make_float4(dd * acc[0] + dd * dd * s[0],
                            dd * acc[1] + dd * dd * s[1],
                            dd * acc[2] + dd * dd * s[2],
                            dd * acc[3] + dd * dd * s[3]);
    }
    __syncthreads();

    // GEMM-h: oh = aggH @ Wc + bc
    int c = t & 15;
    int sl2 = t >> 4;
    int onode = blockIdx.x * 16 + sl2;
    float4 oh = *reinterpret_cast<const float4*>(bc + c * 4);
    {
        const float* arow = &aggH[sl2 * 68];
        #pragma unroll 16
        for (int k = 0; k < 64; k++) {
            float av = arow[k];
            float4 wv = *reinterpret_cast<const float4*>(&Wl[k * 64 + c * 4]);
            oh.x += av * wv.x; oh.y += av * wv.y; oh.z += av * wv.z; oh.w += av * wv.w;
        }
    }
    if (FINAL) {
        *reinterpret_cast<float4*>(foutF + (size_t)onode * 64 + c * 4) = oh;
        return;
    }
    oh.x = fmaxf(oh.x, 0.f); oh.y = fmaxf(oh.y, 0.f);
    oh.z = fmaxf(oh.z, 0.f); oh.w = fmaxf(oh.w, 0.f);

    __syncthreads();
    // restage Wp
    {
        const float4* W4 = reinterpret_cast<const float4*>(Wp);
        float4* Wl4 = reinterpret_cast<float4*>(Wl);
        #pragma unroll
        for (int i = 0; i < 4; i++) Wl4[t + 256 * i] = W4[t + 256 * i];
    }
    __syncthreads();

    // GEMM-p: op = relu(aggP @ Wp + bp)
    float4 op = *reinterpret_cast<const float4*>(bp + c * 4);
    {
        const float* arow = &aggP[sl2 * 68];
        #pragma unroll 16
        for (int k = 0; k < 64; k++) {
            float av = arow[k];
            float4 wv = *reinterpret_cast<const float4*>(&Wl[k * 64 + c * 4]);
            op.x += av * wv.x; op.y += av * wv.y; op.z += av * wv.z; op.w += av * wv.w;
        }
    }
    op.x = fmaxf(op.x, 0.f); op.y = fmaxf(op.y, 0.f);
    op.z = fmaxf(op.z, 0.f); op.w = fmaxf(op.w, 0.f);

    uint2* out2 = reinterpret_cast<uint2*>(out);
    {
        __half2 a = __floats2half2_rn(oh.x + op.x, oh.y + op.y);
        __half2 b = __floats2half2_rn(oh.z + op.z, oh.w + op.w);
        uint2 u;
        u.x = *reinterpret_cast<unsigned int*>(&a);
        u.y = *reinterpret_cast<unsigned int*>(&b);
        out2[(size_t)onode * 32 + c] = u;
    }
    if (write_pe) {
        __half2 a = __floats2half2_rn(op.x, op.y);
        __half2 b = __floats2half2_rn(op.z, op.w);
        uint2 u;
        u.x = *reinterpret_cast<unsigned int*>(&a);
        u.y = *reinterpret_cast<unsigned int*>(&b);
        out2[(size_t)onode * 32 + 16 + c] = u;
    }
}

// ---------------- batchnorm + pool ----------------

__global__ void k_bnstats(const float* __restrict__ h, float* __restrict__ stats) {
    __shared__ float s1[256], s2[256];
    int t = threadIdx.x;
    int f = t & 63, sl = t >> 6;
    float a = 0.f, b = 0.f;
    for (int node = blockIdx.x * 4 + sl; node < NN; node += gridDim.x * 4) {
        float v = h[node * 64 + f];
        a += v;
        b += v * v;
    }
    s1[t] = a;
    s2[t] = b;
    __syncthreads();
    if (t < 64) {
        a = s1[t] + s1[t + 64] + s1[t + 128] + s1[t + 192];
        b = s2[t] + s2[t + 64] + s2[t + 128] + s2[t + 192];
        atomicAdd(&stats[t], a);
        atomicAdd(&stats[64 + t], b);
    }
}

__global__ void k_bnfinal(float* stats) {
    int f = threadIdx.x;
    if (f < 64) {
        float mu = stats[f] / (float)NN;
        float var = stats[64 + f] / (float)NN - mu * mu;
        stats[f] = mu;
        stats[64 + f] = rsqrtf(var + 1e-5f);
    }
}

__global__ void k_pool(const float* __restrict__ h, const float* __restrict__ stats,
                       const float* __restrict__ gamma, const float* __restrict__ beta,
                       const int* __restrict__ ptr, float* __restrict__ out) {
    int g = blockIdx.x;
    int f = threadIdx.x;
    int s = ptr[g], e = ptr[g + 1];
    float mu = stats[f], rstd = stats[64 + f], ga = gamma[f], be = beta[f];
    float acc = 0.f;
    for (int n = s; n < e; n++) {
        float v = (h[n * 64 + f] - mu) * rstd * ga + be;
        acc += fmaxf(v, 0.f);
    }
    out[g * 64 + f] = acc / (float)(e - s);
}

// ---------------- launch ----------------

extern "C" void kernel_launch(void* const* d_in, const int* in_sizes, int n_in,
                              void* d_out, int out_size, void* d_ws, size_t ws_size,
                              hipStream_t stream) {
    const float* x    = (const float*)d_in[0];
    const float* rwpe = (const float*)d_in[1];
    const float* Wrw  = (const float*)d_in[2];
    const float* brw  = (const float*)d_in[3];
    const float *Wc[5], *bc[5], *Wp[5], *bp[5];
    for (int i = 0; i < 5; i++) {
        Wc[i] = (const float*)d_in[4 + 4 * i];
        bc[i] = (const float*)d_in[5 + 4 * i];
        Wp[i] = (const float*)d_in[6 + 4 * i];
        bp[i] = (const float*)d_in[7 + 4 * i];
    }
    const float* gamma = (const float*)d_in[24];
    const float* beta  = (const float*)d_in[25];
    const int* ei  = (const int*)d_in[26];
    const int* ptr = (const int*)d_in[27];
    float* out = (float*)d_out;

    char* wsp = (char*)d_ws;
    auto alloc = [&](size_t bytes) { void* p = (void*)wsp; wsp += ((bytes + 255) / 256) * 256; return p; };
    int*    deg   = (int*)alloc(NN * 4);
    int*    rowp  = (int*)alloc((NN + 1) * 4);
    int*    fill  = (int*)alloc(NN * 4);
    int2*   meta  = (int2*)alloc((size_t)NE * 8);
    float*  dinv  = (float*)alloc(NN * 4);
    __half* bufP  = (__half*)alloc((size_t)NN * 128 * 2);   // interleaved [hs|pe]
    __half* bufQ  = (__half*)alloc((size_t)NN * 128 * 2);
    float*  bufF  = (float*)alloc((size_t)NN * 64 * 4);     // final conv5 out fp32
    float*  stats = (float*)alloc(512);
    int*    bsum  = (int*)alloc(256 * 4);

    hipMemsetAsync(deg, 0, NN * 4, stream);
    hipMemsetAsync(stats, 0, 512, stream);

    const int* srcA = ei;
    const int* dstA = ei + NE;

    dim3 b256(256);
    int gE = (NE + 255) / 256;
    int gN = (NN + 255) / 256;
    int gNode16 = NN / 16;                            // 3125 (exact)
    int gFill = ((NE + CHUNK_E - 1) / CHUNK_E) * 8;   // 391 * 8 = 3128

    k_deg<<<gE, b256, 0, stream>>>(dstA, deg);
    k_dinv<<<gN, b256, 0, stream>>>(deg, dinv);
    k_scan1<<<gN, b256, 0, stream>>>(deg, rowp, bsum);
    k_scan2<<<1, b256, 0, stream>>>(bsum, gN);
    k_scan3<<<gN, b256, 0, stream>>>(rowp, bsum, fill);
    k_csr_fill_xcd<<<gFill, b256, 0, stream>>>(srcA, dstA, dinv, fill, meta);

    k_pe<<<(NN + 3) / 4, b256, 0, stream>>>(x, rwpe, Wrw, brw, bufP);

    // K0..K3: dual convs; K3 skips dead pe write
    k_dual<false><<<gNode16, b256, 0, stream>>>(
        bufP, dinv, rowp, meta, Wc[0], bc[0], Wp[0], bp[0], bufQ, 1, nullptr);
    k_dual<false><<<gNode16, b256, 0, stream>>>(
        bufQ, dinv, rowp, meta, Wc[1], bc[1], Wp[1], bp[1], bufP, 1, nullptr);
    k_dual<false><<<gNode16, b256, 0, stream>>>(
        bufP, dinv, rowp, meta, Wc[2], bc[2], Wp[2], bp[2], bufQ, 1, nullptr);
    k_dual<false><<<gNode16, b256, 0, stream>>>(
        bufQ, dinv, rowp, meta, Wc[3], bc[3], Wp[3], bp[3], bufP, 0, nullptr);
    // K4: final conv (hs only) -> fp32
    k_dual<true><<<gNode16, b256, 0, stream>>>(
        bufP, dinv, rowp, meta, Wc[4], bc[4], nullptr, nullptr, nullptr, 0, bufF);

    k_bnstats<<<256, b256, 0, stream>>>(bufF, stats);
    k_bnfinal<<<1, 64, 0, stream>>>(stats);
    k_pool<<<NG, 64, 0, stream>>>(bufF, stats, gamma, beta, ptr, out);
}

// Round 8
// 358.057 us; speedup vs baseline: 2.0284x; 1.0155x over previous
//
#include <hip/hip_runtime.h>
#include <hip/hip_fp16.h>

#define NN 50000
#define NE 800000
#define FD 64
#define PD 20
#define NG 500
#define NXCD 8
#define DRANGE 6250            // NN / NXCD
#define CHUNK_E 2048

// ---------------- setup kernels ----------------

// XCD-partitioned degree count: block b -> xcd lane (b & 7), edge chunk (b >> 3).
// deg lines for one dst-range are only touched from one XCD lane -> no line bouncing.
__global__ void k_deg_xcd(const int* __restrict__ dstA, int* __restrict__ deg) {
    int xcd = blockIdx.x & 7;
    int chunk = blockIdx.x >> 3;
    int lo = xcd * DRANGE;
    int hi = lo + DRANGE;
    int base = chunk * CHUNK_E;
    int end = min(base + CHUNK_E, NE);
    for (int i = base + threadIdx.x; i < end; i += 256) {
        int d = dstA[i];
        if (d >= lo && d < hi) atomicAdd(&deg[d], 1);
    }
}

// scan1 + dinv fused
__global__ void k_scan1(const int* __restrict__ deg, int* __restrict__ rowp,
                        int* __restrict__ bsum, float* __restrict__ dinv) {
    __shared__ int lds[256];
    int t = threadIdx.x;
    int idx = blockIdx.x * 256 + t;
    int v = (idx < NN) ? deg[idx] : 0;
    if (idx < NN) dinv[idx] = rsqrtf((float)v + 1.0f);
    lds[t] = v;
    __syncthreads();
    for (int off = 1; off < 256; off <<= 1) {
        int add = (t >= off) ? lds[t - off] : 0;
        __syncthreads();
        lds[t] += add;
        __syncthreads();
    }
    if (idx < NN) rowp[idx + 1] = lds[t];
    if (t == 255) bsum[blockIdx.x] = lds[255];
}

__global__ void k_scan2(int* bsum, int nB) {
    __shared__ int lds[256];
    int t = threadIdx.x;
    lds[t] = (t < nB) ? bsum[t] : 0;
    __syncthreads();
    for (int off = 1; off < 256; off <<= 1) {
        int add = (t >= off) ? lds[t - off] : 0;
        __syncthreads();
        lds[t] += add;
        __syncthreads();
    }
    if (t < nB) bsum[t] = lds[t];
}

// finalize rowp AND produce fill[] (fill[i] = rowp[i]) in one pass
__global__ void k_scan3(int* __restrict__ rowp, const int* __restrict__ bsum,
                        int* __restrict__ fill) {
    int idx = blockIdx.x * 256 + threadIdx.x;
    if (idx == 0) { rowp[0] = 0; fill[0] = 0; }
    if (idx < NN) {
        int v = rowp[idx + 1];
        if (blockIdx.x > 0) { v += bsum[blockIdx.x - 1]; rowp[idx + 1] = v; }
        if (idx + 1 < NN) fill[idx + 1] = v;
    }
}

// XCD-partitioned CSR fill
__global__ void k_csr_fill_xcd(const int* __restrict__ srcA, const int* __restrict__ dstA,
                               const float* __restrict__ dinv,
                               int* __restrict__ fill, int2* __restrict__ meta) {
    int xcd = blockIdx.x & 7;
    int chunk = blockIdx.x >> 3;
    int lo = xcd * DRANGE;
    int hi = lo + DRANGE;
    int base = chunk * CHUNK_E;
    int end = min(base + CHUNK_E, NE);
    for (int i = base + threadIdx.x; i < end; i += 256) {
        int d = dstA[i];
        if (d >= lo && d < hi) {
            int s = srcA[i];
            int pos = atomicAdd(&fill[d], 1);
            int2 m;
            m.x = s;
            m.y = __float_as_int(dinv[s]);
            meta[pos] = m;
        }
    }
}

// ---------------- compute kernels ----------------

// pe = RWPE @ W_rw + b_rw ; writes interleaved fp16 row: [hs = x+pe | pe]
__global__ void k_pe(const float* __restrict__ x, const float* __restrict__ rwpe,
                     const float* __restrict__ Wrw, const float* __restrict__ brw,
                     __half* __restrict__ outI) {
    __shared__ float Wl[PD * FD];
    __shared__ float rows[4 * PD];
    int t = threadIdx.x;
    int nodeBase = blockIdx.x * 4;
    for (int i = t; i < PD * FD; i += 256) Wl[i] = Wrw[i];
    if (t < 4 * PD) {
        int n = nodeBase + t / PD;
        rows[t] = (n < NN) ? rwpe[n * PD + (t % PD)] : 0.f;
    }
    __syncthreads();
    int f = t & 63, sl = t >> 6;
    int node = nodeBase + sl;
    if (node < NN) {
        float acc = brw[f];
        #pragma unroll
        for (int k = 0; k < PD; k++) acc += rows[sl * PD + k] * Wl[k * FD + f];
        outI[(size_t)node * 128 + f]      = __float2half_rn(x[node * FD + f] + acc);
        outI[(size_t)node * 128 + 64 + f] = __float2half_rn(acc);
    }
}

__device__ inline void acc8(float* acc, uint4 v, float w) {
    const __half2* h = reinterpret_cast<const __half2*>(&v);
    float2 f0 = __half22float2(h[0]);
    float2 f1 = __half22float2(h[1]);
    float2 f2 = __half22float2(h[2]);
    float2 f3 = __half22float2(h[3]);
    acc[0] += w * f0.x; acc[1] += w * f0.y;
    acc[2] += w * f1.x; acc[3] += w * f1.y;
    acc[4] += w * f2.x; acc[5] += w * f2.y;
    acc[6] += w * f3.x; acc[7] += w * f3.y;
}

__device__ inline void acc4(float* acc, uint2 v, float w) {
    const __half2* h = reinterpret_cast<const __half2*>(&v);
    float2 f0 = __half22float2(h[0]);
    float2 f1 = __half22float2(h[1]);
    acc[0] += w * f0.x; acc[1] += w * f0.y;
    acc[2] += w * f1.x; acc[3] += w * f1.y;
}

// Fused dual GCN conv on interleaved fp16 state rows [hs(64)|pe(64)].
template <bool FINAL>
__global__ __launch_bounds__(256) void k_dual(
    const __half* __restrict__ in,
    const float* __restrict__ dinv, const int* __restrict__ rowp,
    const int2* __restrict__ meta,
    const float* __restrict__ Wc, const float* __restrict__ bc,
    const float* __restrict__ Wp, const float* __restrict__ bp,
    __half* __restrict__ out, int write_pe,
    float* __restrict__ foutF)
{
    __shared__ float Wl[64 * 64];
    __shared__ float aggH[16 * 68];
    __shared__ float aggP[16 * 68];
    int t = threadIdx.x;

    // stage Wc
    {
        const float4* W4 = reinterpret_cast<const float4*>(Wc);
        float4* Wl4 = reinterpret_cast<float4*>(Wl);
        #pragma unroll
        for (int i = 0; i < 4; i++) Wl4[t + 256 * i] = W4[t + 256 * i];
    }

    int l = t & 15;
    int sl = t >> 4;
    int node = blockIdx.x * 16 + sl;
    int e0 = rowp[node], e1 = rowp[node + 1];
    float dd = dinv[node];

    if (!FINAL) {
        const uint4* base = reinterpret_cast<const uint4*>(in);   // row = 16 uint4
        float acc[8] = {0, 0, 0, 0, 0, 0, 0, 0};
        int e = e0;
        for (; e + 4 <= e1; e += 4) {
            int2 m0 = meta[e + 0];
            int2 m1 = meta[e + 1];
            int2 m2 = meta[e + 2];
            int2 m3 = meta[e + 3];
            uint4 v0 = base[(size_t)m0.x * 16 + l];
            uint4 v1 = base[(size_t)m1.x * 16 + l];
            uint4 v2 = base[(size_t)m2.x * 16 + l];
            uint4 v3 = base[(size_t)m3.x * 16 + l];
            acc8(acc, v0, __int_as_float(m0.y));
            acc8(acc, v1, __int_as_float(m1.y));
            acc8(acc, v2, __int_as_float(m2.y));
            acc8(acc, v3, __int_as_float(m3.y));
        }
        for (; e < e1; ++e) {
            int2 m = meta[e];
            acc8(acc, base[(size_t)m.x * 16 + l], __int_as_float(m.y));
        }
        float s[8];
        {
            uint4 sv = base[(size_t)node * 16 + l];
            const __half2* h = reinterpret_cast<const __half2*>(&sv);
            float2 f0 = __half22float2(h[0]);
            float2 f1 = __half22float2(h[1]);
            float2 f2 = __half22float2(h[2]);
            float2 f3 = __half22float2(h[3]);
            s[0] = f0.x; s[1] = f0.y; s[2] = f1.x; s[3] = f1.y;
            s[4] = f2.x; s[5] = f2.y; s[6] = f3.x; s[7] = f3.y;
        }
        float* dst = (l < 8) ? &aggH[sl * 68 + l * 8] : &aggP[sl * 68 + (l - 8) * 8];
        float4* d4 = reinterpret_cast<float4*>(dst);
        d4[0] = make_float4(dd * acc[0] + dd * dd * s[0],
                            dd * acc[1] + dd * dd * s[1],
                            dd * acc[2] + dd * dd * s[2],
                            dd * acc[3] + dd * dd * s[3]);
        d4[1] = make_float4(dd * acc[4] + dd * dd * s[4],
                            dd * acc[5] + dd * dd * s[5],
                            dd * acc[6] + dd * dd * s[6],
                            dd * acc[7] + dd * dd * s[7]);
    } else {
        const uint2* base2 = reinterpret_cast<const uint2*>(in);  // row = 32 uint2, hs = first 16
        float acc[4] = {0, 0, 0, 0};
        int e = e0;
        for (; e + 4 <= e1; e += 4) {
            int2 m0 = meta[e + 0];
            int2 m1 = meta[e + 1];
            int2 m2 = meta[e + 2];
            int2 m3 = meta[e + 3];
            uint2 v0 = base2[(size_t)m0.x * 32 + l];
            uint2 v1 = base2[(size_t)m1.x * 32 + l];
            uint2 v2 = base2[(size_t)m2.x * 32 + l];
            uint2 v3 = base2[(size_t)m3.x * 32 + l];
            acc4(acc, v0, __int_as_float(m0.y));
            acc4(acc, v1, __int_as_float(m1.y));
            acc4(acc, v2, __int_as_float(m2.y));
            acc4(acc, v3, __int_as_float(m3.y));
        }
        for (; e < e1; ++e) {
            int2 m = meta[e];
            acc4(acc, base2[(size_t)m.x * 32 + l], __int_as_float(m.y));
        }
        float s[4];
        {
            uint2 sv = base2[(size_t)node * 32 + l];
            const __half2* h = reinterpret_cast<const __half2*>(&sv);
            float2 f0 = __half22float2(h[0]);
            float2 f1 = __half22float2(h[1]);
            s[0] = f0.x; s[1] = f0.y; s[2] = f1.x; s[3] = f1.y;
        }
        float4* d4 = reinterpret_cast<float4*>(&aggH[sl * 68 + l * 4]);
        d4[0] = make_float4(dd * acc[0] + dd * dd * s[0],
                            dd * acc[1] + dd * dd * s[1],
                            dd * acc[2] + dd * dd * s[2],
                            dd * acc[3] + dd * dd * s[3]);
    }
    __syncthreads();

    // GEMM-h: oh = aggH @ Wc + bc
    int c = t & 15;
    int sl2 = t >> 4;
    int onode = blockIdx.x * 16 + sl2;
    float4 oh = *reinterpret_cast<const float4*>(bc + c * 4);
    {
        const float* arow = &aggH[sl2 * 68];
        #pragma unroll 16
        for (int k = 0; k < 64; k++) {
            float av = arow[k];
            float4 wv = *reinterpret_cast<const float4*>(&Wl[k * 64 + c * 4]);
            oh.x += av * wv.x; oh.y += av * wv.y; oh.z += av * wv.z; oh.w += av * wv.w;
        }
    }
    if (FINAL) {
        *reinterpret_cast<float4*>(foutF + (size_t)onode * 64 + c * 4) = oh;
        return;
    }
    oh.x = fmaxf(oh.x, 0.f); oh.y = fmaxf(oh.y, 0.f);
    oh.z = fmaxf(oh.z, 0.f); oh.w = fmaxf(oh.w, 0.f);

    __syncthreads();
    // restage Wp
    {
        const float4* W4 = reinterpret_cast<const float4*>(Wp);
        float4* Wl4 = reinterpret_cast<float4*>(Wl);
        #pragma unroll
        for (int i = 0; i < 4; i++) Wl4[t + 256 * i] = W4[t + 256 * i];
    }
    __syncthreads();

    // GEMM-p: op = relu(aggP @ Wp + bp)
    float4 op = *reinterpret_cast<const float4*>(bp + c * 4);
    {
        const float* arow = &aggP[sl2 * 68];
        #pragma unroll 16
        for (int k = 0; k < 64; k++) {
            float av = arow[k];
            float4 wv = *reinterpret_cast<const float4*>(&Wl[k * 64 + c * 4]);
            op.x += av * wv.x; op.y += av * wv.y; op.z += av * wv.z; op.w += av * wv.w;
        }
    }
    op.x = fmaxf(op.x, 0.f); op.y = fmaxf(op.y, 0.f);
    op.z = fmaxf(op.z, 0.f); op.w = fmaxf(op.w, 0.f);

    uint2* out2 = reinterpret_cast<uint2*>(out);
    {
        __half2 a = __floats2half2_rn(oh.x + op.x, oh.y + op.y);
        __half2 b = __floats2half2_rn(oh.z + op.z, oh.w + op.w);
        uint2 u;
        u.x = *reinterpret_cast<unsigned int*>(&a);
        u.y = *reinterpret_cast<unsigned int*>(&b);
        out2[(size_t)onode * 32 + c] = u;
    }
    if (write_pe) {
        __half2 a = __floats2half2_rn(op.x, op.y);
        __half2 b = __floats2half2_rn(op.z, op.w);
        uint2 u;
        u.x = *reinterpret_cast<unsigned int*>(&a);
        u.y = *reinterpret_cast<unsigned int*>(&b);
        out2[(size_t)onode * 32 + 16 + c] = u;
    }
}

// ---------------- batchnorm + pool ----------------

__global__ void k_bnstats(const float* __restrict__ h, float* __restrict__ stats) {
    __shared__ float s1[256], s2[256];
    int t = threadIdx.x;
    int f = t & 63, sl = t >> 6;
    float a = 0.f, b = 0.f;
    for (int node = blockIdx.x * 4 + sl; node < NN; node += gridDim.x * 4) {
        float v = h[node * 64 + f];
        a += v;
        b += v * v;
    }
    s1[t] = a;
    s2[t] = b;
    __syncthreads();
    if (t < 64) {
        a = s1[t] + s1[t + 64] + s1[t + 128] + s1[t + 192];
        b = s2[t] + s2[t + 64] + s2[t + 128] + s2[t + 192];
        atomicAdd(&stats[t], a);
        atomicAdd(&stats[64 + t], b);
    }
}

__global__ void k_bnfinal(float* stats) {
    int f = threadIdx.x;
    if (f < 64) {
        float mu = stats[f] / (float)NN;
        float var = stats[64 + f] / (float)NN - mu * mu;
        stats[f] = mu;
        stats[64 + f] = rsqrtf(var + 1e-5f);
    }
}

__global__ void k_pool(const float* __restrict__ h, const float* __restrict__ stats,
                       const float* __restrict__ gamma, const float* __restrict__ beta,
                       const int* __restrict__ ptr, float* __restrict__ out) {
    int g = blockIdx.x;
    int f = threadIdx.x;
    int s = ptr[g], e = ptr[g + 1];
    float mu = stats[f], rstd = stats[64 + f], ga = gamma[f], be = beta[f];
    float acc = 0.f;
    for (int n = s; n < e; n++) {
        float v = (h[n * 64 + f] - mu) * rstd * ga + be;
        acc += fmaxf(v, 0.f);
    }
    out[g * 64 + f] = acc / (float)(e - s);
}

// ---------------- launch ----------------

extern "C" void kernel_launch(void* const* d_in, const int* in_sizes, int n_in,
                              void* d_out, int out_size, void* d_ws, size_t ws_size,
                              hipStream_t stream) {
    const float* x    = (const float*)d_in[0];
    const float* rwpe = (const float*)d_in[1];
    const float* Wrw  = (const float*)d_in[2];
    const float* brw  = (const float*)d_in[3];
    const float *Wc[5], *bc[5], *Wp[5], *bp[5];
    for (int i = 0; i < 5; i++) {
        Wc[i] = (const float*)d_in[4 + 4 * i];
        bc[i] = (const float*)d_in[5 + 4 * i];
        Wp[i] = (const float*)d_in[6 + 4 * i];
        bp[i] = (const float*)d_in[7 + 4 * i];
    }
    const float* gamma = (const float*)d_in[24];
    const float* beta  = (const float*)d_in[25];
    const int* ei  = (const int*)d_in[26];
    const int* ptr = (const int*)d_in[27];
    float* out = (float*)d_out;

    char* wsp = (char*)d_ws;
    auto alloc = [&](size_t bytes) { void* p = (void*)wsp; wsp += ((bytes + 255) / 256) * 256; return p; };
    int*    deg   = (int*)alloc(NN * 4);
    int*    rowp  = (int*)alloc((NN + 1) * 4);
    int*    fill  = (int*)alloc(NN * 4);
    int2*   meta  = (int2*)alloc((size_t)NE * 8);
    float*  dinv  = (float*)alloc(NN * 4);
    __half* bufP  = (__half*)alloc((size_t)NN * 128 * 2);   // interleaved [hs|pe]
    __half* bufQ  = (__half*)alloc((size_t)NN * 128 * 2);
    float*  bufF  = (float*)alloc((size_t)NN * 64 * 4);     // final conv5 out fp32
    float*  stats = (float*)alloc(512);
    int*    bsum  = (int*)alloc(256 * 4);

    hipMemsetAsync(deg, 0, NN * 4, stream);
    hipMemsetAsync(stats, 0, 512, stream);

    const int* srcA = ei;
    const int* dstA = ei + NE;

    dim3 b256(256);
    int gN = (NN + 255) / 256;
    int gNode16 = NN / 16;                            // 3125 (exact)
    int gFill = ((NE + CHUNK_E - 1) / CHUNK_E) * 8;   // 391 * 8 = 3128

    k_deg_xcd<<<gFill, b256, 0, stream>>>(dstA, deg);
    k_scan1<<<gN, b256, 0, stream>>>(deg, rowp, bsum, dinv);
    k_scan2<<<1, b256, 0, stream>>>(bsum, gN);
    k_scan3<<<gN, b256, 0, stream>>>(rowp, bsum, fill);
    k_csr_fill_xcd<<<gFill, b256, 0, stream>>>(srcA, dstA, dinv, fill, meta);

    k_pe<<<(NN + 3) / 4, b256, 0, stream>>>(x, rwpe, Wrw, brw, bufP);

    // K0..K3: dual convs; K3 skips dead pe write
    k_dual<false><<<gNode16, b256, 0, stream>>>(
        bufP, dinv, rowp, meta, Wc[0], bc[0], Wp[0], bp[0], bufQ, 1, nullptr);
    k_dual<false><<<gNode16, b256, 0, stream>>>(
        bufQ, dinv, rowp, meta, Wc[1], bc[1], Wp[1], bp[1], bufP, 1, nullptr);
    k_dual<false><<<gNode16, b256, 0, stream>>>(
        bufP, dinv, rowp, meta, Wc[2], bc[2], Wp[2], bp[2], bufQ, 1, nullptr);
    k_dual<false><<<gNode16, b256, 0, stream>>>(
        bufQ, dinv, rowp, meta, Wc[3], bc[3], Wp[3], bp[3], bufP, 0, nullptr);
    // K4: final conv (hs only) -> fp32
    k_dual<true><<<gNode16, b256, 0, stream>>>(
        bufP, dinv, rowp, meta, Wc[4], bc[4], nullptr, nullptr, nullptr, 0, bufF);

    k_bnstats<<<256, b256, 0, stream>>>(bufF, stats);
    k_bnfinal<<<1, 64, 0, stream>>>(stats);
    k_pool<<<NG, 64, 0, stream>>>(bufF, stats, gamma, beta, ptr, out);
}

// Round 9
// 340.504 us; speedup vs baseline: 2.1329x; 1.0516x over previous
//
#include <hip/hip_runtime.h>
#include <hip/hip_fp16.h>

#define NN 50000
#define NE 800000
#define FD 64
#define PD 20
#define NG 500
#define NXCD 8
#define DRANGE 6250            // NN / NXCD
#define CHUNK_E 2048

// ---------------- setup kernels ----------------

__global__ void k_deg_xcd(const int* __restrict__ dstA, int* __restrict__ deg) {
    int xcd = blockIdx.x & 7;
    int chunk = blockIdx.x >> 3;
    int lo = xcd * DRANGE;
    int hi = lo + DRANGE;
    int base = chunk * CHUNK_E;
    int end = min(base + CHUNK_E, NE);
    for (int i = base + threadIdx.x; i < end; i += 256) {
        int d = dstA[i];
        if (d >= lo && d < hi) atomicAdd(&deg[d], 1);
    }
}

// scan1 + dinv fused
__global__ void k_scan1(const int* __restrict__ deg, int* __restrict__ rowp,
                        int* __restrict__ bsum, float* __restrict__ dinv) {
    __shared__ int lds[256];
    int t = threadIdx.x;
    int idx = blockIdx.x * 256 + t;
    int v = (idx < NN) ? deg[idx] : 0;
    if (idx < NN) dinv[idx] = rsqrtf((float)v + 1.0f);
    lds[t] = v;
    __syncthreads();
    for (int off = 1; off < 256; off <<= 1) {
        int add = (t >= off) ? lds[t - off] : 0;
        __syncthreads();
        lds[t] += add;
        __syncthreads();
    }
    if (idx < NN) rowp[idx + 1] = lds[t];
    if (t == 255) bsum[blockIdx.x] = lds[255];
}

__global__ void k_scan2(int* bsum, int nB) {
    __shared__ int lds[256];
    int t = threadIdx.x;
    lds[t] = (t < nB) ? bsum[t] : 0;
    __syncthreads();
    for (int off = 1; off < 256; off <<= 1) {
        int add = (t >= off) ? lds[t - off] : 0;
        __syncthreads();
        lds[t] += add;
        __syncthreads();
    }
    if (t < nB) bsum[t] = lds[t];
}

__global__ void k_scan3(int* __restrict__ rowp, const int* __restrict__ bsum,
                        int* __restrict__ fill) {
    int idx = blockIdx.x * 256 + threadIdx.x;
    if (idx == 0) { rowp[0] = 0; fill[0] = 0; }
    if (idx < NN) {
        int v = rowp[idx + 1];
        if (blockIdx.x > 0) { v += bsum[blockIdx.x - 1]; rowp[idx + 1] = v; }
        if (idx + 1 < NN) fill[idx + 1] = v;
    }
}

__global__ void k_csr_fill_xcd(const int* __restrict__ srcA, const int* __restrict__ dstA,
                               const float* __restrict__ dinv,
                               int* __restrict__ fill, int2* __restrict__ meta) {
    int xcd = blockIdx.x & 7;
    int chunk = blockIdx.x >> 3;
    int lo = xcd * DRANGE;
    int hi = lo + DRANGE;
    int base = chunk * CHUNK_E;
    int end = min(base + CHUNK_E, NE);
    for (int i = base + threadIdx.x; i < end; i += 256) {
        int d = dstA[i];
        if (d >= lo && d < hi) {
            int s = srcA[i];
            int pos = atomicAdd(&fill[d], 1);
            int2 m;
            m.x = s;
            m.y = __float_as_int(dinv[s]);
            meta[pos] = m;
        }
    }
}

// ---------------- compute kernels ----------------

// pe = RWPE @ W_rw + b_rw ; writes interleaved fp16 row: [hs = x+pe | pe]
__global__ void k_pe(const float* __restrict__ x, const float* __restrict__ rwpe,
                     const float* __restrict__ Wrw, const float* __restrict__ brw,
                     __half* __restrict__ outI) {
    __shared__ float Wl[PD * FD];
    __shared__ float rows[4 * PD];
    int t = threadIdx.x;
    int nodeBase = blockIdx.x * 4;
    for (int i = t; i < PD * FD; i += 256) Wl[i] = Wrw[i];
    if (t < 4 * PD) {
        int n = nodeBase + t / PD;
        rows[t] = (n < NN) ? rwpe[n * PD + (t % PD)] : 0.f;
    }
    __syncthreads();
    int f = t & 63, sl = t >> 6;
    int node = nodeBase + sl;
    if (node < NN) {
        float acc = brw[f];
        #pragma unroll
        for (int k = 0; k < PD; k++) acc += rows[sl * PD + k] * Wl[k * FD + f];
        outI[(size_t)node * 128 + f]      = __float2half_rn(x[node * FD + f] + acc);
        outI[(size_t)node * 128 + 64 + f] = __float2half_rn(acc);
    }
}

__device__ inline void acc8(float* acc, uint4 v, float w) {
    const __half2* h = reinterpret_cast<const __half2*>(&v);
    float2 f0 = __half22float2(h[0]);
    float2 f1 = __half22float2(h[1]);
    float2 f2 = __half22float2(h[2]);
    float2 f3 = __half22float2(h[3]);
    acc[0] += w * f0.x; acc[1] += w * f0.y;
    acc[2] += w * f1.x; acc[3] += w * f1.y;
    acc[4] += w * f2.x; acc[5] += w * f2.y;
    acc[6] += w * f3.x; acc[7] += w * f3.y;
}

__device__ inline void acc4(float* acc, uint2 v, float w) {
    const __half2* h = reinterpret_cast<const __half2*>(&v);
    float2 f0 = __half22float2(h[0]);
    float2 f1 = __half22float2(h[1]);
    acc[0] += w * f0.x; acc[1] += w * f0.y;
    acc[2] += w * f1.x; acc[3] += w * f1.y;
}

// Fused dual GCN conv on interleaved fp16 state rows [hs(64)|pe(64)].
// Gather phase: meta loaded once per 16-edge chunk by the slot's 16 lanes
// (lane l -> meta[e0+cb+l]) and broadcast per-edge via __shfl (LDS pipe,
// no vmcnt). Row gathers issued in groups of 8 independent loads.
template <bool FINAL>
__global__ __launch_bounds__(256) void k_dual(
    const __half* __restrict__ in,
    const float* __restrict__ dinv, const int* __restrict__ rowp,
    const int2* __restrict__ meta,
    const float* __restrict__ Wc, const float* __restrict__ bc,
    const float* __restrict__ Wp, const float* __restrict__ bp,
    __half* __restrict__ out, int write_pe,
    float* __restrict__ foutF)
{
    __shared__ float Wl[64 * 64];
    __shared__ float aggH[16 * 68];
    __shared__ float aggP[16 * 68];
    int t = threadIdx.x;

    // stage Wc
    {
        const float4* W4 = reinterpret_cast<const float4*>(Wc);
        float4* Wl4 = reinterpret_cast<float4*>(Wl);
        #pragma unroll
        for (int i = 0; i < 4; i++) Wl4[t + 256 * i] = W4[t + 256 * i];
    }

    int l = t & 15;            // lane within slot
    int sl = t >> 4;           // slot in block 0..15
    int ws = (t >> 4) & 3;     // slot within wave 0..3
    int node = blockIdx.x * 16 + sl;
    int e0 = rowp[node], e1 = rowp[node + 1];
    int cnt = e1 - e0;
    float dd = dinv[node];

    if (!FINAL) {
        const uint4* base = reinterpret_cast<const uint4*>(in);   // row = 16 uint4
        float acc[8] = {0, 0, 0, 0, 0, 0, 0, 0};
        for (int cb = 0; cb < cnt; cb += 16) {
            int midx = min(e0 + cb + l, NE - 1);
            int2 mreg = meta[midx];
            int rem = cnt - cb;                    // >= 1
            int src0 = __shfl(mreg.x, ws * 16, 64);   // first edge of chunk (valid)
            #pragma unroll
            for (int g = 0; g < 2; g++) {
                if (g == 1 && rem <= 8) break;     // slot-uniform branch
                int srcj[8]; float wj[8];
                #pragma unroll
                for (int jj = 0; jj < 8; jj++) {
                    int j = g * 8 + jj;
                    int sx = __shfl(mreg.x, ws * 16 + j, 64);
                    float ww = __int_as_float(__shfl(mreg.y, ws * 16 + j, 64));
                    bool valid = (j < rem);
                    srcj[jj] = valid ? sx : src0;  // padded loads hit L1 (same row)
                    wj[jj] = valid ? ww : 0.f;
                }
                uint4 v0 = base[(size_t)srcj[0] * 16 + l];
                uint4 v1 = base[(size_t)srcj[1] * 16 + l];
                uint4 v2 = base[(size_t)srcj[2] * 16 + l];
                uint4 v3 = base[(size_t)srcj[3] * 16 + l];
                uint4 v4 = base[(size_t)srcj[4] * 16 + l];
                uint4 v5 = base[(size_t)srcj[5] * 16 + l];
                uint4 v6 = base[(size_t)srcj[6] * 16 + l];
                uint4 v7 = base[(size_t)srcj[7] * 16 + l];
                acc8(acc, v0, wj[0]);
                acc8(acc, v1, wj[1]);
                acc8(acc, v2, wj[2]);
                acc8(acc, v3, wj[3]);
                acc8(acc, v4, wj[4]);
                acc8(acc, v5, wj[5]);
                acc8(acc, v6, wj[6]);
                acc8(acc, v7, wj[7]);
            }
        }
        float s[8];
        {
            uint4 sv = base[(size_t)node * 16 + l];
            const __half2* h = reinterpret_cast<const __half2*>(&sv);
            float2 f0 = __half22float2(h[0]);
            float2 f1 = __half22float2(h[1]);
            float2 f2 = __half22float2(h[2]);
            float2 f3 = __half22float2(h[3]);
            s[0] = f0.x; s[1] = f0.y; s[2] = f1.x; s[3] = f1.y;
            s[4] = f2.x; s[5] = f2.y; s[6] = f3.x; s[7] = f3.y;
        }
        float* dst = (l < 8) ? &aggH[sl * 68 + l * 8] : &aggP[sl * 68 + (l - 8) * 8];
        float4* d4 = reinterpret_cast<float4*>(dst);
        d4[0] = make_float4(dd * acc[0] + dd * dd * s[0],
                            dd * acc[1] + dd * dd * s[1],
                            dd * acc[2] + dd * dd * s[2],
                            dd * acc[3] + dd * dd * s[3]);
        d4[1] = make_float4(dd * acc[4] + dd * dd * s[4],
                            dd * acc[5] + dd * dd * s[5],
                            dd * acc[6] + dd * dd * s[6],
                            dd * acc[7] + dd * dd * s[7]);
    } else {
        const uint2* base2 = reinterpret_cast<const uint2*>(in);  // row = 32 uint2
        float acc[4] = {0, 0, 0, 0};
        for (int cb = 0; cb < cnt; cb += 16) {
            int midx = min(e0 + cb + l, NE - 1);
            int2 mreg = meta[midx];
            int rem = cnt - cb;
            int src0 = __shfl(mreg.x, ws * 16, 64);
            #pragma unroll
            for (int g = 0; g < 2; g++) {
                if (g == 1 && rem <= 8) break;
                int srcj[8]; float wj[8];
                #pragma unroll
                for (int jj = 0; jj < 8; jj++) {
                    int j = g * 8 + jj;
                    int sx = __shfl(mreg.x, ws * 16 + j, 64);
                    float ww = __int_as_float(__shfl(mreg.y, ws * 16 + j, 64));
                    bool valid = (j < rem);
                    srcj[jj] = valid ? sx : src0;
                    wj[jj] = valid ? ww : 0.f;
                }
                uint2 v0 = base2[(size_t)srcj[0] * 32 + l];
                uint2 v1 = base2[(size_t)srcj[1] * 32 + l];
                uint2 v2 = base2[(size_t)srcj[2] * 32 + l];
                uint2 v3 = base2[(size_t)srcj[3] * 32 + l];
                uint2 v4 = base2[(size_t)srcj[4] * 32 + l];
                uint2 v5 = base2[(size_t)srcj[5] * 32 + l];
                uint2 v6 = base2[(size_t)srcj[6] * 32 + l];
                uint2 v7 = base2[(size_t)srcj[7] * 32 + l];
                acc4(acc, v0, wj[0]);
                acc4(acc, v1, wj[1]);
                acc4(acc, v2, wj[2]);
                acc4(acc, v3, wj[3]);
                acc4(acc, v4, wj[4]);
                acc4(acc, v5, wj[5]);
                acc4(acc, v6, wj[6]);
                acc4(acc, v7, wj[7]);
            }
        }
        float s[4];
        {
            uint2 sv = base2[(size_t)node * 32 + l];
            const __half2* h = reinterpret_cast<const __half2*>(&sv);
            float2 f0 = __half22float2(h[0]);
            float2 f1 = __half22float2(h[1]);
            s[0] = f0.x; s[1] = f0.y; s[2] = f1.x; s[3] = f1.y;
        }
        float4* d4 = reinterpret_cast<float4*>(&aggH[sl * 68 + l * 4]);
        d4[0] = make_float4(dd * acc[0] + dd * dd * s[0],
                            dd * acc[1] + dd * dd * s[1],
                            dd * acc[2] + dd * dd * s[2],
                            dd * acc[3] + dd * dd * s[3]);
    }
    __syncthreads();

    // GEMM-h: oh = aggH @ Wc + bc
    int c = t & 15;
    int sl2 = t >> 4;
    int onode = blockIdx.x * 16 + sl2;
    float4 oh = *reinterpret_cast<const float4*>(bc + c * 4);
    {
        const float* arow = &aggH[sl2 * 68];
        #pragma unroll 16
        for (int k = 0; k < 64; k++) {
            float av = arow[k];
            float4 wv = *reinterpret_cast<const float4*>(&Wl[k * 64 + c * 4]);
            oh.x += av * wv.x; oh.y += av * wv.y; oh.z += av * wv.z; oh.w += av * wv.w;
        }
    }
    if (FINAL) {
        *reinterpret_cast<float4*>(foutF + (size_t)onode * 64 + c * 4) = oh;
        return;
    }
    oh.x = fmaxf(oh.x, 0.f); oh.y = fmaxf(oh.y, 0.f);
    oh.z = fmaxf(oh.z, 0.f); oh.w = fmaxf(oh.w, 0.f);

    __syncthreads();
    // restage Wp
    {
        const float4* W4 = reinterpret_cast<const float4*>(Wp);
        float4* Wl4 = reinterpret_cast<float4*>(Wl);
        #pragma unroll
        for (int i = 0; i < 4; i++) Wl4[t + 256 * i] = W4[t + 256 * i];
    }
    __syncthreads();

    // GEMM-p: op = relu(aggP @ Wp + bp)
    float4 op = *reinterpret_cast<const float4*>(bp + c * 4);
    {
        const float* arow = &aggP[sl2 * 68];
        #pragma unroll 16
        for (int k = 0; k < 64; k++) {
            float av = arow[k];
            float4 wv = *reinterpret_cast<const float4*>(&Wl[k * 64 + c * 4]);
            op.x += av * wv.x; op.y += av * wv.y; op.z += av * wv.z; op.w += av * wv.w;
        }
    }
    op.x = fmaxf(op.x, 0.f); op.y = fmaxf(op.y, 0.f);
    op.z = fmaxf(op.z, 0.f); op.w = fmaxf(op.w, 0.f);

    uint2* out2 = reinterpret_cast<uint2*>(out);
    {
        __half2 a = __floats2half2_rn(oh.x + op.x, oh.y + op.y);
        __half2 b = __floats2half2_rn(oh.z + op.z, oh.w + op.w);
        uint2 u;
        u.x = *reinterpret_cast<unsigned int*>(&a);
        u.y = *reinterpret_cast<unsigned int*>(&b);
        out2[(size_t)onode * 32 + c] = u;
    }
    if (write_pe) {
        __half2 a = __floats2half2_rn(op.x, op.y);
        __half2 b = __floats2half2_rn(op.z, op.w);
        uint2 u;
        u.x = *reinterpret_cast<unsigned int*>(&a);
        u.y = *reinterpret_cast<unsigned int*>(&b);
        out2[(size_t)onode * 32 + 16 + c] = u;
    }
}

// ---------------- batchnorm + pool ----------------

__global__ void k_bnstats(const float* __restrict__ h, float* __restrict__ stats) {
    __shared__ float s1[256], s2[256];
    int t = threadIdx.x;
    int f = t & 63, sl = t >> 6;
    float a = 0.f, b = 0.f;
    for (int node = blockIdx.x * 4 + sl; node < NN; node += gridDim.x * 4) {
        float v = h[node * 64 + f];
        a += v;
        b += v * v;
    }
    s1[t] = a;
    s2[t] = b;
    __syncthreads();
    if (t < 64) {
        a = s1[t] + s1[t + 64] + s1[t + 128] + s1[t + 192];
        b = s2[t] + s2[t + 64] + s2[t + 128] + s2[t + 192];
        atomicAdd(&stats[t], a);
        atomicAdd(&stats[64 + t], b);
    }
}

__global__ void k_bnfinal(float* stats) {
    int f = threadIdx.x;
    if (f < 64) {
        float mu = stats[f] / (float)NN;
        float var = stats[64 + f] / (float)NN - mu * mu;
        stats[f] = mu;
        stats[64 + f] = rsqrtf(var + 1e-5f);
    }
}

__global__ void k_pool(const float* __restrict__ h, const float* __restrict__ stats,
                       const float* __restrict__ gamma, const float* __restrict__ beta,
                       const int* __restrict__ ptr, float* __restrict__ out) {
    int g = blockIdx.x;
    int f = threadIdx.x;
    int s = ptr[g], e = ptr[g + 1];
    float mu = stats[f], rstd = stats[64 + f], ga = gamma[f], be = beta[f];
    float acc = 0.f;
    for (int n = s; n < e; n++) {
        float v = (h[n * 64 + f] - mu) * rstd * ga + be;
        acc += fmaxf(v, 0.f);
    }
    out[g * 64 + f] = acc / (float)(e - s);
}

// ---------------- launch ----------------

extern "C" void kernel_launch(void* const* d_in, const int* in_sizes, int n_in,
                              void* d_out, int out_size, void* d_ws, size_t ws_size,
                              hipStream_t stream) {
    const float* x    = (const float*)d_in[0];
    const float* rwpe = (const float*)d_in[1];
    const float* Wrw  = (const float*)d_in[2];
    const float* brw  = (const float*)d_in[3];
    const float *Wc[5], *bc[5], *Wp[5], *bp[5];
    for (int i = 0; i < 5; i++) {
        Wc[i] = (const float*)d_in[4 + 4 * i];
        bc[i] = (const float*)d_in[5 + 4 * i];
        Wp[i] = (const float*)d_in[6 + 4 * i];
        bp[i] = (const float*)d_in[7 + 4 * i];
    }
    const float* gamma = (const float*)d_in[24];
    const float* beta  = (const float*)d_in[25];
    const int* ei  = (const int*)d_in[26];
    const int* ptr = (const int*)d_in[27];
    float* out = (float*)d_out;

    char* wsp = (char*)d_ws;
    auto alloc = [&](size_t bytes) { void* p = (void*)wsp; wsp += ((bytes + 255) / 256) * 256; return p; };
    int*    deg   = (int*)alloc(NN * 4);
    int*    rowp  = (int*)alloc((NN + 1) * 4);
    int*    fill  = (int*)alloc(NN * 4);
    int2*   meta  = (int2*)alloc((size_t)NE * 8);
    float*  dinv  = (float*)alloc(NN * 4);
    __half* bufP  = (__half*)alloc((size_t)NN * 128 * 2);   // interleaved [hs|pe]
    __half* bufQ  = (__half*)alloc((size_t)NN * 128 * 2);
    float*  bufF  = (float*)alloc((size_t)NN * 64 * 4);     // final conv5 out fp32
    float*  stats = (float*)alloc(512);
    int*    bsum  = (int*)alloc(256 * 4);

    hipMemsetAsync(deg, 0, NN * 4, stream);
    hipMemsetAsync(stats, 0, 512, stream);

    const int* srcA = ei;
    const int* dstA = ei + NE;

    dim3 b256(256);
    int gN = (NN + 255) / 256;
    int gNode16 = NN / 16;                            // 3125 (exact)
    int gFill = ((NE + CHUNK_E - 1) / CHUNK_E) * 8;   // 391 * 8 = 3128

    k_deg_xcd<<<gFill, b256, 0, stream>>>(dstA, deg);
    k_scan1<<<gN, b256, 0, stream>>>(deg, rowp, bsum, dinv);
    k_scan2<<<1, b256, 0, stream>>>(bsum, gN);
    k_scan3<<<gN, b256, 0, stream>>>(rowp, bsum, fill);
    k_csr_fill_xcd<<<gFill, b256, 0, stream>>>(srcA, dstA, dinv, fill, meta);

    k_pe<<<(NN + 3) / 4, b256, 0, stream>>>(x, rwpe, Wrw, brw, bufP);

    // K0..K3: dual convs; K3 skips dead pe write
    k_dual<false><<<gNode16, b256, 0, stream>>>(
        bufP, dinv, rowp, meta, Wc[0], bc[0], Wp[0], bp[0], bufQ, 1, nullptr);
    k_dual<false><<<gNode16, b256, 0, stream>>>(
        bufQ, dinv, rowp, meta, Wc[1], bc[1], Wp[1], bp[1], bufP, 1, nullptr);
    k_dual<false><<<gNode16, b256, 0, stream>>>(
        bufP, dinv, rowp, meta, Wc[2], bc[2], Wp[2], bp[2], bufQ, 1, nullptr);
    k_dual<false><<<gNode16, b256, 0, stream>>>(
        bufQ, dinv, rowp, meta, Wc[3], bc[3], Wp[3], bp[3], bufP, 0, nullptr);
    // K4: final conv (hs only) -> fp32
    k_dual<true><<<gNode16, b256, 0, stream>>>(
        bufP, dinv, rowp, meta, Wc[4], bc[4], nullptr, nullptr, nullptr, 0, bufF);

    k_bnstats<<<256, b256, 0, stream>>>(bufF, stats);
    k_bnfinal<<<1, 64, 0, stream>>>(stats);
    k_pool<<<NG, 64, 0, stream>>>(bufF, stats, gamma, beta, ptr, out);
}